// Round 6
// baseline (605.643 us; speedup 1.0000x reference)
//
#include <hip/hip_runtime.h>
#include <hip/hip_bf16.h>
#include <cstdint>

#define N_NODES 8192
#define DDIM    64
#define DX      128
#define NEDGE   262144
#define BR      64
#define BC      64
#define SPLITS  8
#define TILES   (N_NODES / BC / SPLITS)   // 16
#define CAP     24                        // max bias edges per row per split (Poisson(4))

typedef float f32x4 __attribute__((ext_vector_type(4)));
typedef short short8 __attribute__((ext_vector_type(8)));

__device__ __forceinline__ short f2bf(float f) {
    union { float f; uint32_t u; } v; v.f = f;
    uint32_t u = v.u;
    uint32_t r = (u + 0x7FFFu + ((u >> 16) & 1u)) >> 16;
    return (short)r;
}
__device__ __forceinline__ float bf2f(short s) {
    union { uint32_t u; float f; } v;
    v.u = ((uint32_t)(uint16_t)s) << 16;
    return v.f;
}

// ---- prep: X = [mag*cos(phase) | mag*sin(phase)] as bf16 [N][128]
__global__ void cpa_prep_x(const float* __restrict__ mag, const float* __restrict__ phase,
                           short* __restrict__ Xbf) {
    int idx = blockIdx.x * 256 + threadIdx.x;      // N*64 threads
    int i = idx >> 6, d = idx & 63;
    float m = mag[idx], p = phase[idx];
    Xbf[i * DX + d]        = f2bf(m * __cosf(p));
    Xbf[i * DX + 64 + d]   = f2bf(m * __sinf(p));
}

// ---- prep: Ybt[c][i] = bf16(Y[i][c]), Y = [mag | phase]  (K-transposed V)
__global__ void cpa_prep_yt(const float* __restrict__ mag, const float* __restrict__ phase,
                            short* __restrict__ Ybt) {
    __shared__ short tile[64][65];
    int bi = blockIdx.x >> 1;
    int bc = blockIdx.x & 1;
    int i0 = bi * 64;
    const float* src = bc ? phase : mag;
    int tid = threadIdx.x;
    for (int itr = 0; itr < 16; ++itr) {
        int idx = tid + itr * 256;                 // 0..4095
        int ii = idx >> 6, cc = idx & 63;
        tile[ii][cc] = f2bf(src[(size_t)(i0 + ii) * 64 + cc]);
    }
    __syncthreads();
    for (int itr = 0; itr < 16; ++itr) {
        int idx = tid + itr * 256;
        int cc = idx >> 6, ii = idx & 63;
        Ybt[(size_t)(bc * 64 + cc) * N_NODES + i0 + ii] = tile[ii][cc];
    }
}

// ---- prep: wsum[k] = sum_h W[h][k], bsum = sum b   (rank-1 collapse of edge Linear)
__global__ void cpa_prep_w(const float* __restrict__ W, const float* __restrict__ b,
                           float* __restrict__ wsb) {
    int t = threadIdx.x;   // 64 threads = 1 wave
    float w0 = W[t * 4 + 0], w1 = W[t * 4 + 1], w2 = W[t * 4 + 2], w3 = W[t * 4 + 3];
    float bb = b[t];
    #pragma unroll
    for (int o = 32; o > 0; o >>= 1) {
        w0 += __shfl_down(w0, o);
        w1 += __shfl_down(w1, o);
        w2 += __shfl_down(w2, o);
        w3 += __shfl_down(w3, o);
        bb += __shfl_down(bb, o);
    }
    if (t == 0) { wsb[0] = w0; wsb[1] = w1; wsb[2] = w2; wsb[3] = w3; wsb[4] = bb; }
}

// ---- edge scores + per-src histogram
__global__ void cpa_edges(const int* __restrict__ ei, const float* __restrict__ ea,
                          const float* __restrict__ wsb, float* __restrict__ es,
                          int* __restrict__ cnt) {
    int e = blockIdx.x * 256 + threadIdx.x;
    float4 a = *(const float4*)(ea + (size_t)e * 4);
    es[e] = a.x * wsb[0] + a.y * wsb[1] + a.z * wsb[2] + a.w * wsb[3] + wsb[4];
    int src = ei[e];
    atomicAdd(&cnt[src], 1);
}

// ---- exclusive scan of 8192 counts (1 block, Hillis-Steele over 256 partials)
__global__ void cpa_scan(const int* __restrict__ cnt, int* __restrict__ rowptr,
                         int* __restrict__ cursor) {
    __shared__ int part[256];
    int t = threadIdx.x;
    int base = t * 32;
    int s = 0;
    for (int k = 0; k < 32; ++k) s += cnt[base + k];
    part[t] = s;
    __syncthreads();
    #pragma unroll
    for (int off = 1; off < 256; off <<= 1) {
        int v = (t >= off) ? part[t - off] : 0;
        __syncthreads();
        part[t] += v;
        __syncthreads();
    }
    if (t == 255) rowptr[N_NODES] = part[255];
    int run = part[t] - s;     // exclusive prefix of this 32-chunk
    for (int k = 0; k < 32; ++k) {
        rowptr[base + k] = run;
        cursor[base + k] = run;
        run += cnt[base + k];
    }
}

// ---- scatter edges into CSR, key = (dst<<18)|e  (sortable by (dst, e))
__global__ void cpa_scatter(const int* __restrict__ ei, int* __restrict__ cursor,
                            int* __restrict__ keys) {
    int e = blockIdx.x * 256 + threadIdx.x;
    int src = ei[e];
    int dst = ei[NEDGE + e];
    int pos = atomicAdd(&cursor[src], 1);
    keys[pos] = (dst << 18) | e;
}

// ---- per-row sort by (dst,e) via wave-parallel bitonic (2 keys/lane, len<=128);
// mark all-but-last duplicate dst dead (numpy last-wins). No scratch, no LDS.
__global__ __launch_bounds__(256) void cpa_sortrows(const int* __restrict__ rowptr,
                                                    int* __restrict__ keys) {
    int row  = blockIdx.x * 4 + (threadIdx.x >> 6);   // one wave per row
    int lane = threadIdx.x & 63;
    int beg = rowptr[row], end = rowptr[row + 1];
    int len = end - beg;
    if (len > 128) len = 128;   // Poisson(32): impossible in practice
    const int idx0 = lane * 2, idx1 = lane * 2 + 1;
    int v0 = (idx0 < len) ? keys[beg + idx0] : 0x7FFFFFFF;
    int v1 = (idx1 < len) ? keys[beg + idx1] : 0x7FFFFFFF;

    #pragma unroll
    for (int k = 2; k <= 128; k <<= 1) {
        #pragma unroll
        for (int j = k >> 1; j >= 2; j >>= 1) {
            int ldist = j >> 1;                        // partner lane distance
            int p0 = __shfl_xor(v0, ldist);
            int p1 = __shfl_xor(v1, ldist);
            bool asc = (idx0 & k) == 0;                // same for both slots (k>=2)
            bool low = (idx0 & j) == 0;                // same for both slots (j>=2)
            int n0 = (low == asc) ? min(v0, p0) : max(v0, p0);
            int n1 = (low == asc) ? min(v1, p1) : max(v1, p1);
            v0 = n0; v1 = n1;
        }
        {   // j == 1: within-lane compare of the two slots
            bool asc = (idx0 & k) == 0;
            int lo = min(v0, v1), hi = max(v0, v1);
            v0 = asc ? lo : hi;
            v1 = asc ? hi : lo;
        }
    }

    // mark dead: element idx is dead iff idx+1 < len and dst(idx+1)==dst(idx).
    int nextv0 = __shfl_down(v0, 1);                   // lane+1's v0 = element idx1+1
    bool dead0 = (idx0 + 1 < len) && ((v0 >> 18) == (v1 >> 18));
    bool dead1 = (idx1 + 1 < len) && ((v1 >> 18) == (nextv0 >> 18));
    if (idx0 < len) keys[beg + idx0] = v0 | (dead0 ? 0x80000000 : 0);
    if (idx1 < len) keys[beg + idx1] = v1 | (dead1 ? 0x80000000 : 0);
}

// ---- flash attention, 64-row block, one column split (1024 cols).
// B-fragments direct from global (16B contiguous). P C->A layout transform is
// intra-wave through a per-wave LDS slice (DS ops in a wave are in-order), so
// the tile loop has ZERO barriers -- waves run as independent pipelines.
// Edge bias applied once at the end (commutes with online-softmax rescaling).
__global__ __launch_bounds__(256, 2) void cpa_flash(
    const short* __restrict__ Xbf, const short* __restrict__ Ybt,
    const float* __restrict__ es, const int* __restrict__ keys,
    const int* __restrict__ rowptr,
    float* __restrict__ msplit, float* __restrict__ lsplit,
    short* __restrict__ Opart)
{
    __shared__ short Pl[BR][72];      // P tile bf16; wave w only touches rows 16w..16w+15
    __shared__ int   corr_dst[BR][CAP];
    __shared__ float corr_f[BR][CAP];
    __shared__ int   ccnt[BR];
    __shared__ float dls[BR];
    __shared__ float mfin[BR];

    const int tid   = threadIdx.x;
    const int lane  = tid & 63;
    const int w     = tid >> 6;       // wave 0..3 -> rows 16w..16w+15
    const int q     = lane >> 4;      // quad
    const int colid = lane & 15;

    const int ib = blockIdx.x;        // 0..127
    const int split = blockIdx.y;     // 0..SPLITS-1
    const int i0 = ib * BR;
    const int jstart = split * (N_NODES / SPLITS);

    // A-fragments straight from global (16B contiguous along features)
    short8 afrag[4];
    #pragma unroll
    for (int kf = 0; kf < 4; ++kf)
        afrag[kf] = *(const short8*)(Xbf + (size_t)(i0 + w * 16 + colid) * DX + kf * 32 + q * 8);

    float m_r[4] = {-1e30f, -1e30f, -1e30f, -1e30f};
    float l_r[4] = {0.f, 0.f, 0.f, 0.f};
    f32x4 O[8];
    #pragma unroll
    for (int t = 0; t < 8; ++t) O[t] = (f32x4){0.f, 0.f, 0.f, 0.f};

    for (int tt = 0; tt < TILES; ++tt) {
        const int j0 = jstart + tt * BC;
        // S = Xi·Xj^T : B-fragments direct from global
        f32x4 S[4];
        #pragma unroll
        for (int st = 0; st < 4; ++st) {
            const short* bbase = Xbf + (size_t)(j0 + st * 16 + colid) * DX + q * 8;
            f32x4 acc = (f32x4){0.f, 0.f, 0.f, 0.f};
            #pragma unroll
            for (int kf = 0; kf < 4; ++kf) {
                short8 bfrag = *(const short8*)(bbase + kf * 32);
                acc = __builtin_amdgcn_mfma_f32_16x16x32_bf16(afrag[kf], bfrag, acc, 0, 0, 0);
            }
            S[st] = acc;
        }
        // online softmax (C-layout: row = q*4+r, col = st*16+colid)
        float mnew[4], alpha[4];
        #pragma unroll
        for (int r = 0; r < 4; ++r) {
            float mx = fmaxf(fmaxf(S[0][r], S[1][r]), fmaxf(S[2][r], S[3][r]));
            mx = fmaxf(mx, __shfl_xor(mx, 1));
            mx = fmaxf(mx, __shfl_xor(mx, 2));
            mx = fmaxf(mx, __shfl_xor(mx, 4));
            mx = fmaxf(mx, __shfl_xor(mx, 8));
            mnew[r] = fmaxf(m_r[r], mx);
            alpha[r] = __expf(m_r[r] - mnew[r]);
            m_r[r] = mnew[r];
        }
        float rsum[4] = {0.f, 0.f, 0.f, 0.f};
        short pb[4][4];
        #pragma unroll
        for (int st = 0; st < 4; ++st) {
            #pragma unroll
            for (int r = 0; r < 4; ++r) {
                float p = __expf(S[st][r] - mnew[r]);
                rsum[r] += p;
                pb[st][r] = f2bf(p);
            }
        }
        #pragma unroll
        for (int r = 0; r < 4; ++r) {
            float s_ = rsum[r];
            s_ += __shfl_xor(s_, 1);
            s_ += __shfl_xor(s_, 2);
            s_ += __shfl_xor(s_, 4);
            s_ += __shfl_xor(s_, 8);
            l_r[r] = l_r[r] * alpha[r] + s_;
            #pragma unroll
            for (int t = 0; t < 8; ++t) O[t][r] *= alpha[r];
        }
        // P -> LDS (intra-wave rows only; DS in-order per wave => no barrier)
        #pragma unroll
        for (int st = 0; st < 4; ++st)
            #pragma unroll
            for (int r = 0; r < 4; ++r)
                Pl[w * 16 + q * 4 + r][st * 16 + colid] = pb[st][r];

        // O += P·Y : P A-frags from LDS (own-wave rows), Y B-frags from global
        short8 pf0 = *(const short8*)&Pl[w * 16 + colid][q * 8];
        short8 pf1 = *(const short8*)&Pl[w * 16 + colid][32 + q * 8];
        #pragma unroll
        for (int t = 0; t < 8; ++t) {
            const short* yb = Ybt + (size_t)(t * 16 + colid) * N_NODES + j0 + q * 8;
            short8 b0 = *(const short8*)(yb);
            short8 b1 = *(const short8*)(yb + 32);
            O[t] = __builtin_amdgcn_mfma_f32_16x16x32_bf16(pf0, b0, O[t], 0, 0, 0);
            O[t] = __builtin_amdgcn_mfma_f32_16x16x32_bf16(pf1, b1, O[t], 0, 0, 0);
        }
    }

    // ---- end-of-split edge-bias correction ----
    if (colid == 0) {
        #pragma unroll
        for (int r = 0; r < 4; ++r) mfin[w * 16 + q * 4 + r] = m_r[r];
    }
    if (tid < BR) ccnt[tid] = 0;
    __syncthreads();

    // walker: one thread per row; fac = (exp(es)-1)*exp(S - m_final)
    if (tid < BR) {
        const int i = i0 + tid;
        int c = rowptr[i];
        const int e_ = rowptr[i + 1];
        const int jend = jstart + N_NODES / SPLITS;
        const float mf = mfin[tid];
        int nc = 0;
        float fs = 0.f;
        while (c < e_) {
            int k = keys[c]; ++c;
            int dst = (k >> 18) & 0x1FFF;
            if (dst < jstart) continue;
            if (dst >= jend) break;          // keys sorted by dst within row
            if (k < 0) continue;             // dead duplicate
            const short* xi = Xbf + (size_t)i * DX;
            const short* xd = Xbf + (size_t)dst * DX;
            float s = 0.f;
            for (int kk = 0; kk < DX; ++kk) s += bf2f(xi[kk]) * bf2f(xd[kk]);
            float fac = (__expf(es[k & 0x3FFFF]) - 1.f) * __expf(s - mf);
            if (nc < CAP) { corr_dst[tid][nc] = dst; corr_f[tid][nc] = fac; ++nc; }
            fs += fac;
        }
        ccnt[tid] = nc;
        dls[tid] = fs;
    }
    __syncthreads();

    // all lanes apply their rows' corrections
    #pragma unroll
    for (int r = 0; r < 4; ++r) {
        int row = w * 16 + q * 4 + r;
        l_r[r] += dls[row];
        int nc = ccnt[row];
        for (int e2 = 0; e2 < nc; ++e2) {
            int dst = corr_dst[row][e2];
            float fac = corr_f[row][e2];
            #pragma unroll
            for (int t = 0; t < 8; ++t)
                O[t][r] += fac * bf2f(Ybt[(size_t)(t * 16 + colid) * N_NODES + dst]);
        }
    }

    // epilogue: store partial m, l, O (O as bf16)
    const int ibase = i0 + w * 16 + q * 4;
    #pragma unroll
    for (int r = 0; r < 4; ++r) {
        if (colid == r) {
            msplit[(size_t)split * N_NODES + ibase + r] = m_r[r];
            lsplit[(size_t)split * N_NODES + ibase + r] = l_r[r];
        }
    }
    #pragma unroll
    for (int t = 0; t < 8; ++t) {
        #pragma unroll
        for (int r = 0; r < 4; ++r) {
            size_t off = ((size_t)split * N_NODES + ibase + r) * DX + t * 16 + colid;
            Opart[off] = f2bf(O[t][r]);
        }
    }
}

// ---- merge splits + normalize + write [new_mag | new_phase]
__global__ void cpa_merge(const float* __restrict__ msplit, const float* __restrict__ lsplit,
                          const short* __restrict__ Opart, float* __restrict__ out) {
    int gid = blockIdx.x * 256 + threadIdx.x;   // N*128 threads
    int i = gid >> 7;
    int c = gid & 127;
    float mm = -1e30f;
    #pragma unroll
    for (int s = 0; s < SPLITS; ++s) mm = fmaxf(mm, msplit[(size_t)s * N_NODES + i]);
    float den = 0.f, num = 0.f;
    #pragma unroll
    for (int s = 0; s < SPLITS; ++s) {
        float wgt = __expf(msplit[(size_t)s * N_NODES + i] - mm);
        den += lsplit[(size_t)s * N_NODES + i] * wgt;
        num += bf2f(Opart[((size_t)s * N_NODES + i) * DX + c]) * wgt;
    }
    float val = num / den;
    if (c < 64) out[(size_t)i * 64 + c] = val;
    else        out[(size_t)N_NODES * 64 + (size_t)i * 64 + (c - 64)] = val;
}

extern "C" void kernel_launch(void* const* d_in, const int* in_sizes, int n_in,
                              void* d_out, int out_size, void* d_ws, size_t ws_size,
                              hipStream_t stream)
{
    const float* mag   = (const float*)d_in[0];
    const float* phase = (const float*)d_in[1];
    const int*   ei    = (const int*)d_in[2];     // edge_index [2][E] (int32 per harness)
    const float* ea    = (const float*)d_in[3];
    const float* W     = (const float*)d_in[4];
    const float* b     = (const float*)d_in[5];
    float* out = (float*)d_out;

    char* ws = (char*)d_ws;
    short* Xbf    = (short*)(ws + 0);               // 2 MB
    short* Ybt    = (short*)(ws + 2097152);         // 2 MB
    float* es     = (float*)(ws + 4194304);         // 1 MB
    int*   keys   = (int*)  (ws + 5242880);         // 1 MB
    int*   rowptr = (int*)  (ws + 6291456);         // 36 KB slot
    int*   cnt    = (int*)  (ws + 6328320);         // 32 KB
    int*   cursor = (int*)  (ws + 6361088);         // 32 KB
    float* wsb    = (float*)(ws + 6393856);         // 256 B
    float* msplit = (float*)(ws + 6394112);         // 256 KB (8 splits)
    float* lsplit = (float*)(ws + 6656256);         // 256 KB
    short* Opart  = (short*)(ws + 6918400);         // 16 MB (bf16, 8 splits)

    hipMemsetAsync(cnt, 0, N_NODES * sizeof(int), stream);
    cpa_prep_x<<<N_NODES * DDIM / 256, 256, 0, stream>>>(mag, phase, Xbf);
    cpa_prep_yt<<<(N_NODES / 64) * 2, 256, 0, stream>>>(mag, phase, Ybt);
    cpa_prep_w<<<1, 64, 0, stream>>>(W, b, wsb);
    cpa_edges<<<NEDGE / 256, 256, 0, stream>>>(ei, ea, wsb, es, cnt);
    cpa_scan<<<1, 256, 0, stream>>>(cnt, rowptr, cursor);
    cpa_scatter<<<NEDGE / 256, 256, 0, stream>>>(ei, cursor, keys);
    cpa_sortrows<<<N_NODES / 4, 256, 0, stream>>>(rowptr, keys);
    cpa_flash<<<dim3(N_NODES / BR, SPLITS), 256, 0, stream>>>(Xbf, Ybt, es, keys, rowptr,
                                                              msplit, lsplit, Opart);
    cpa_merge<<<N_NODES * DX / 256, 256, 0, stream>>>(msplit, lsplit, Opart, out);
}

// Round 8
// 511.806 us; speedup vs baseline: 1.1833x; 1.1833x over previous
//
#include <hip/hip_runtime.h>
#include <hip/hip_bf16.h>
#include <cstdint>

#define N_NODES 8192
#define DDIM    64
#define DX      128
#define NEDGE   262144
#define BR      64
#define BC      64
#define SPLITS  6
#define CAP     24   // max bias edges per row per split (Poisson(~5.3); P(>24)~1e-9)

typedef float f32x4 __attribute__((ext_vector_type(4)));
typedef short short8 __attribute__((ext_vector_type(8)));

__device__ __forceinline__ short f2bf(float f) {
    union { float f; uint32_t u; } v; v.f = f;
    uint32_t u = v.u;
    uint32_t r = (u + 0x7FFFu + ((u >> 16) & 1u)) >> 16;
    return (short)r;
}
__device__ __forceinline__ float bf2f(short s) {
    union { uint32_t u; float f; } v;
    v.u = ((uint32_t)(uint16_t)s) << 16;
    return v.f;
}

// ---- prep: X = [mag*cos(phase) | mag*sin(phase)] as bf16 [N][128]
__global__ void cpa_prep_x(const float* __restrict__ mag, const float* __restrict__ phase,
                           short* __restrict__ Xbf) {
    int idx = blockIdx.x * 256 + threadIdx.x;      // N*64 threads
    int i = idx >> 6, d = idx & 63;
    float m = mag[idx], p = phase[idx];
    Xbf[i * DX + d]        = f2bf(m * __cosf(p));
    Xbf[i * DX + 64 + d]   = f2bf(m * __sinf(p));
}

// ---- prep: Ybt[c][i] = bf16(Y[i][c]), Y = [mag | phase]  (K-transposed V)
__global__ void cpa_prep_yt(const float* __restrict__ mag, const float* __restrict__ phase,
                            short* __restrict__ Ybt) {
    __shared__ short tile[64][65];
    int bi = blockIdx.x >> 1;
    int bc = blockIdx.x & 1;
    int i0 = bi * 64;
    const float* src = bc ? phase : mag;
    int tid = threadIdx.x;
    for (int itr = 0; itr < 16; ++itr) {
        int idx = tid + itr * 256;                 // 0..4095
        int ii = idx >> 6, cc = idx & 63;
        tile[ii][cc] = f2bf(src[(size_t)(i0 + ii) * 64 + cc]);
    }
    __syncthreads();
    for (int itr = 0; itr < 16; ++itr) {
        int idx = tid + itr * 256;
        int cc = idx >> 6, ii = idx & 63;
        Ybt[(size_t)(bc * 64 + cc) * N_NODES + i0 + ii] = tile[ii][cc];
    }
}

// ---- prep: wsum[k] = sum_h W[h][k], bsum = sum b   (rank-1 collapse of edge Linear)
__global__ void cpa_prep_w(const float* __restrict__ W, const float* __restrict__ b,
                           float* __restrict__ wsb) {
    int t = threadIdx.x;   // 64 threads = 1 wave
    float w0 = W[t * 4 + 0], w1 = W[t * 4 + 1], w2 = W[t * 4 + 2], w3 = W[t * 4 + 3];
    float bb = b[t];
    #pragma unroll
    for (int o = 32; o > 0; o >>= 1) {
        w0 += __shfl_down(w0, o);
        w1 += __shfl_down(w1, o);
        w2 += __shfl_down(w2, o);
        w3 += __shfl_down(w3, o);
        bb += __shfl_down(bb, o);
    }
    if (t == 0) { wsb[0] = w0; wsb[1] = w1; wsb[2] = w2; wsb[3] = w3; wsb[4] = bb; }
}

// ---- edge scores + per-src histogram
__global__ void cpa_edges(const int* __restrict__ ei, const float* __restrict__ ea,
                          const float* __restrict__ wsb, float* __restrict__ es,
                          int* __restrict__ cnt) {
    int e = blockIdx.x * 256 + threadIdx.x;
    float4 a = *(const float4*)(ea + (size_t)e * 4);
    es[e] = a.x * wsb[0] + a.y * wsb[1] + a.z * wsb[2] + a.w * wsb[3] + wsb[4];
    int src = ei[e];
    atomicAdd(&cnt[src], 1);
}

// ---- exclusive scan of 8192 counts (1 block, Hillis-Steele over 256 partials)
__global__ void cpa_scan(const int* __restrict__ cnt, int* __restrict__ rowptr,
                         int* __restrict__ cursor) {
    __shared__ int part[256];
    int t = threadIdx.x;
    int base = t * 32;
    int s = 0;
    for (int k = 0; k < 32; ++k) s += cnt[base + k];
    part[t] = s;
    __syncthreads();
    #pragma unroll
    for (int off = 1; off < 256; off <<= 1) {
        int v = (t >= off) ? part[t - off] : 0;
        __syncthreads();
        part[t] += v;
        __syncthreads();
    }
    if (t == 255) rowptr[N_NODES] = part[255];
    int run = part[t] - s;     // exclusive prefix of this 32-chunk
    for (int k = 0; k < 32; ++k) {
        rowptr[base + k] = run;
        cursor[base + k] = run;
        run += cnt[base + k];
    }
}

// ---- scatter edges into CSR, key = (dst<<18)|e  (sortable by (dst, e))
__global__ void cpa_scatter(const int* __restrict__ ei, int* __restrict__ cursor,
                            int* __restrict__ keys) {
    int e = blockIdx.x * 256 + threadIdx.x;
    int src = ei[e];
    int dst = ei[NEDGE + e];
    int pos = atomicAdd(&cursor[src], 1);
    keys[pos] = (dst << 18) | e;
}

// ---- per-row sort by (dst,e) via wave-parallel bitonic (2 keys/lane, len<=128);
// mark all-but-last duplicate dst dead (numpy last-wins). No scratch, no LDS.
__global__ __launch_bounds__(256) void cpa_sortrows(const int* __restrict__ rowptr,
                                                    int* __restrict__ keys) {
    int row  = blockIdx.x * 4 + (threadIdx.x >> 6);   // one wave per row
    int lane = threadIdx.x & 63;
    int beg = rowptr[row], end = rowptr[row + 1];
    int len = end - beg;
    if (len > 128) len = 128;   // Poisson(32): impossible in practice
    const int idx0 = lane * 2, idx1 = lane * 2 + 1;
    int v0 = (idx0 < len) ? keys[beg + idx0] : 0x7FFFFFFF;
    int v1 = (idx1 < len) ? keys[beg + idx1] : 0x7FFFFFFF;

    #pragma unroll
    for (int k = 2; k <= 128; k <<= 1) {
        #pragma unroll
        for (int j = k >> 1; j >= 2; j >>= 1) {
            int ldist = j >> 1;                        // partner lane distance
            int p0 = __shfl_xor(v0, ldist);
            int p1 = __shfl_xor(v1, ldist);
            bool asc = (idx0 & k) == 0;                // same for both slots (k>=2)
            bool low = (idx0 & j) == 0;                // same for both slots (j>=2)
            int n0 = (low == asc) ? min(v0, p0) : max(v0, p0);
            int n1 = (low == asc) ? min(v1, p1) : max(v1, p1);
            v0 = n0; v1 = n1;
        }
        {   // j == 1: within-lane compare of the two slots
            bool asc = (idx0 & k) == 0;
            int lo = min(v0, v1), hi = max(v0, v1);
            v0 = asc ? lo : hi;
            v1 = asc ? hi : lo;
        }
    }

    // mark dead: element idx is dead iff idx+1 < len and dst(idx+1)==dst(idx).
    int nextv0 = __shfl_down(v0, 1);                   // lane+1's v0 = element idx1+1
    bool dead0 = (idx0 + 1 < len) && ((v0 >> 18) == (v1 >> 18));
    bool dead1 = (idx1 + 1 < len) && ((v1 >> 18) == (nextv0 >> 18));
    if (idx0 < len) keys[beg + idx0] = v0 | (dead0 ? 0x80000000 : 0);
    if (idx1 < len) keys[beg + idx1] = v1 | (dead1 ? 0x80000000 : 0);
}

// ---- flash attention, 64-row block, one column split (uneven: 22 or 21 tiles).
// R4-proven LDS staging for both S and PV B-fragments. P C->A round trip is
// intra-wave (rows 16w..16w+15 only) => no barrier. 2 barriers/tile total.
// Edge bias applied once at the end (commutes with online-softmax rescaling);
// correction arrays overlay the Xj staging buffer (dead after the loop).
__global__ __launch_bounds__(256) void cpa_flash(
    const short* __restrict__ Xbf, const short* __restrict__ Ybt,
    const float* __restrict__ es, const int* __restrict__ keys,
    const int* __restrict__ rowptr,
    float* __restrict__ msplit, float* __restrict__ lsplit,
    short* __restrict__ Opart)
{
    __shared__ short Xj[BR][136];     // X tile (j rows), stride 136 (16B-aligned rows)
    __shared__ short Yt[DX][72];      // V tile K-transposed: Yt[feature][j-local]
    __shared__ short Pl[BR][72];      // P tile bf16; wave w touches rows 16w..16w+15 only
    __shared__ int   ccnt[BR];
    __shared__ float dls[BR];
    __shared__ float mfin[BR];

    const int tid   = threadIdx.x;
    const int lane  = tid & 63;
    const int w     = tid >> 6;       // wave 0..3 -> rows 16w..16w+15
    const int q     = lane >> 4;      // quad
    const int colid = lane & 15;

    const int ib = blockIdx.x;        // 0..127
    const int split = blockIdx.y;     // 0..SPLITS-1
    const int i0 = ib * BR;
    const int tbase  = split * 21 + min(split, 2);       // 128 col-tiles over 6 splits
    const int ntiles = 21 + (split < 2 ? 1 : 0);
    const int jstart = tbase * BC;
    const int jend   = jstart + ntiles * BC;

    // A-fragments straight from global (16B contiguous along features, one-time)
    short8 afrag[4];
    #pragma unroll
    for (int kf = 0; kf < 4; ++kf)
        afrag[kf] = *(const short8*)(Xbf + (size_t)(i0 + w * 16 + colid) * DX + kf * 32 + q * 8);

    float m_r[4] = {-1e30f, -1e30f, -1e30f, -1e30f};
    float l_r[4] = {0.f, 0.f, 0.f, 0.f};
    f32x4 O[8];
    #pragma unroll
    for (int t = 0; t < 8; ++t) O[t] = (f32x4){0.f, 0.f, 0.f, 0.f};

    for (int tt = 0; tt < ntiles; ++tt) {
        const int j0 = jstart + tt * BC;
        // phase A: stage X_j and Y_t tiles (cooperative, vectorized)
        for (int itr = 0; itr < 4; ++itr) {
            int idx = tid + itr * 256;
            int r = idx >> 4;
            int c8 = (idx & 15) << 3;
            *(int4*)(&Xj[r][c8]) = *(const int4*)(Xbf + (size_t)(j0 + r) * DX + c8);
        }
        for (int itr = 0; itr < 4; ++itr) {
            int idx = tid + itr * 256;
            int n = idx >> 3;
            int k8 = (idx & 7) << 3;
            *(int4*)(&Yt[n][k8]) = *(const int4*)(Ybt + (size_t)n * N_NODES + j0 + k8);
        }
        __syncthreads();  // B1: staging visible

        // phase B: S = Xi·Xj^T
        f32x4 S[4];
        #pragma unroll
        for (int st = 0; st < 4; ++st) {
            f32x4 acc = (f32x4){0.f, 0.f, 0.f, 0.f};
            #pragma unroll
            for (int kf = 0; kf < 4; ++kf) {
                short8 bfrag = *(const short8*)&Xj[st * 16 + colid][kf * 32 + q * 8];
                acc = __builtin_amdgcn_mfma_f32_16x16x32_bf16(afrag[kf], bfrag, acc, 0, 0, 0);
            }
            S[st] = acc;
        }
        // online softmax (C-layout: row = q*4+r, col = st*16+colid)
        float mnew[4], alpha[4];
        #pragma unroll
        for (int r = 0; r < 4; ++r) {
            float mx = fmaxf(fmaxf(S[0][r], S[1][r]), fmaxf(S[2][r], S[3][r]));
            mx = fmaxf(mx, __shfl_xor(mx, 1));
            mx = fmaxf(mx, __shfl_xor(mx, 2));
            mx = fmaxf(mx, __shfl_xor(mx, 4));
            mx = fmaxf(mx, __shfl_xor(mx, 8));
            mnew[r] = fmaxf(m_r[r], mx);
            alpha[r] = __expf(m_r[r] - mnew[r]);
            m_r[r] = mnew[r];
        }
        float rsum[4] = {0.f, 0.f, 0.f, 0.f};
        short pb[4][4];
        #pragma unroll
        for (int st = 0; st < 4; ++st) {
            #pragma unroll
            for (int r = 0; r < 4; ++r) {
                float p = __expf(S[st][r] - mnew[r]);
                rsum[r] += p;
                pb[st][r] = f2bf(p);
            }
        }
        #pragma unroll
        for (int r = 0; r < 4; ++r) {
            float s_ = rsum[r];
            s_ += __shfl_xor(s_, 1);
            s_ += __shfl_xor(s_, 2);
            s_ += __shfl_xor(s_, 4);
            s_ += __shfl_xor(s_, 8);
            l_r[r] = l_r[r] * alpha[r] + s_;
            #pragma unroll
            for (int t = 0; t < 8; ++t) O[t][r] *= alpha[r];
        }
        // P -> LDS (intra-wave rows; DS same-wave ordering => no barrier)
        #pragma unroll
        for (int st = 0; st < 4; ++st)
            #pragma unroll
            for (int r = 0; r < 4; ++r)
                Pl[w * 16 + q * 4 + r][st * 16 + colid] = pb[st][r];

        // phase D: O += P·Y
        short8 pf0 = *(const short8*)&Pl[w * 16 + colid][q * 8];
        short8 pf1 = *(const short8*)&Pl[w * 16 + colid][32 + q * 8];
        #pragma unroll
        for (int t = 0; t < 8; ++t) {
            short8 b0 = *(const short8*)&Yt[t * 16 + colid][q * 8];
            short8 b1 = *(const short8*)&Yt[t * 16 + colid][32 + q * 8];
            O[t] = __builtin_amdgcn_mfma_f32_16x16x32_bf16(pf0, b0, O[t], 0, 0, 0);
            O[t] = __builtin_amdgcn_mfma_f32_16x16x32_bf16(pf1, b1, O[t], 0, 0, 0);
        }
        __syncthreads();  // B4: WAR fence before next tile's staging
    }

    // ---- end-of-split edge-bias correction ----
    // corr arrays overlay Xj (dead after the tile loop; last B4 already fenced)
    int*   corr_dst = (int*)&Xj[0][0];                 // 64*CAP ints  (6144 B)
    float* corr_f   = (float*)&Xj[0][0] + BR * CAP;    // 64*CAP floats (6144 B) — fits in 17.4 KB

    if (colid == 0) {
        #pragma unroll
        for (int r = 0; r < 4; ++r) mfin[w * 16 + q * 4 + r] = m_r[r];
    }
    if (tid < BR) ccnt[tid] = 0;
    __syncthreads();

    // walker: one thread per row; fac = (exp(es)-1)*exp(S_recomputed - m_final)
    if (tid < BR) {
        const int i = i0 + tid;
        int c = rowptr[i];
        const int e_ = rowptr[i + 1];
        const float mf = mfin[tid];
        int nc = 0;
        float fs = 0.f;
        while (c < e_) {
            int k = keys[c]; ++c;
            int dst = (k >> 18) & 0x1FFF;
            if (dst < jstart) continue;
            if (dst >= jend) break;          // keys sorted by dst within row
            if (k < 0) continue;             // dead duplicate
            const short* xi = Xbf + (size_t)i * DX;
            const short* xd = Xbf + (size_t)dst * DX;
            float s = 0.f;
            for (int kk = 0; kk < DX; ++kk) s += bf2f(xi[kk]) * bf2f(xd[kk]);
            float fac = (__expf(es[k & 0x3FFFF]) - 1.f) * __expf(s - mf);
            if (nc < CAP) { corr_dst[tid * CAP + nc] = dst; corr_f[tid * CAP + nc] = fac; ++nc; }
            fs += fac;
        }
        ccnt[tid] = nc;
        dls[tid] = fs;
    }
    __syncthreads();

    // all lanes apply their rows' corrections
    #pragma unroll
    for (int r = 0; r < 4; ++r) {
        int row = w * 16 + q * 4 + r;
        l_r[r] += dls[row];
        int nc = ccnt[row];
        for (int e2 = 0; e2 < nc; ++e2) {
            int dst = corr_dst[row * CAP + e2];
            float fac = corr_f[row * CAP + e2];
            #pragma unroll
            for (int t = 0; t < 8; ++t)
                O[t][r] += fac * bf2f(Ybt[(size_t)(t * 16 + colid) * N_NODES + dst]);
        }
    }

    // epilogue: store partial m, l, O (O as bf16)
    const int ibase = i0 + w * 16 + q * 4;
    #pragma unroll
    for (int r = 0; r < 4; ++r) {
        if (colid == r) {
            msplit[(size_t)split * N_NODES + ibase + r] = m_r[r];
            lsplit[(size_t)split * N_NODES + ibase + r] = l_r[r];
        }
    }
    #pragma unroll
    for (int t = 0; t < 8; ++t) {
        #pragma unroll
        for (int r = 0; r < 4; ++r) {
            size_t off = ((size_t)split * N_NODES + ibase + r) * DX + t * 16 + colid;
            Opart[off] = f2bf(O[t][r]);
        }
    }
}

// ---- merge splits + normalize + write [new_mag | new_phase]
__global__ void cpa_merge(const float* __restrict__ msplit, const float* __restrict__ lsplit,
                          const short* __restrict__ Opart, float* __restrict__ out) {
    int gid = blockIdx.x * 256 + threadIdx.x;   // N*128 threads
    int i = gid >> 7;
    int c = gid & 127;
    float mm = -1e30f;
    #pragma unroll
    for (int s = 0; s < SPLITS; ++s) mm = fmaxf(mm, msplit[(size_t)s * N_NODES + i]);
    float den = 0.f, num = 0.f;
    #pragma unroll
    for (int s = 0; s < SPLITS; ++s) {
        float wgt = __expf(msplit[(size_t)s * N_NODES + i] - mm);
        den += lsplit[(size_t)s * N_NODES + i] * wgt;
        num += bf2f(Opart[((size_t)s * N_NODES + i) * DX + c]) * wgt;
    }
    float val = num / den;
    if (c < 64) out[(size_t)i * 64 + c] = val;
    else        out[(size_t)N_NODES * 64 + (size_t)i * 64 + (c - 64)] = val;
}

extern "C" void kernel_launch(void* const* d_in, const int* in_sizes, int n_in,
                              void* d_out, int out_size, void* d_ws, size_t ws_size,
                              hipStream_t stream)
{
    const float* mag   = (const float*)d_in[0];
    const float* phase = (const float*)d_in[1];
    const int*   ei    = (const int*)d_in[2];     // edge_index [2][E] (int32 per harness)
    const float* ea    = (const float*)d_in[3];
    const float* W     = (const float*)d_in[4];
    const float* b     = (const float*)d_in[5];
    float* out = (float*)d_out;

    char* ws = (char*)d_ws;
    short* Xbf    = (short*)(ws + 0);               // 2 MB
    short* Ybt    = (short*)(ws + 2097152);         // 2 MB
    float* es     = (float*)(ws + 4194304);         // 1 MB
    int*   keys   = (int*)  (ws + 5242880);         // 1 MB
    int*   rowptr = (int*)  (ws + 6291456);         // 36 KB slot
    int*   cnt    = (int*)  (ws + 6328320);         // 32 KB
    int*   cursor = (int*)  (ws + 6361088);         // 32 KB
    float* wsb    = (float*)(ws + 6393856);         // 256 B
    float* msplit = (float*)(ws + 6394112);         // 256 KB slot (6 splits used)
    float* lsplit = (float*)(ws + 6656256);         // 256 KB slot
    short* Opart  = (short*)(ws + 6918400);         // 12.6 MB (bf16, 6 splits)

    hipMemsetAsync(cnt, 0, N_NODES * sizeof(int), stream);
    cpa_prep_x<<<N_NODES * DDIM / 256, 256, 0, stream>>>(mag, phase, Xbf);
    cpa_prep_yt<<<(N_NODES / 64) * 2, 256, 0, stream>>>(mag, phase, Ybt);
    cpa_prep_w<<<1, 64, 0, stream>>>(W, b, wsb);
    cpa_edges<<<NEDGE / 256, 256, 0, stream>>>(ei, ea, wsb, es, cnt);
    cpa_scan<<<1, 256, 0, stream>>>(cnt, rowptr, cursor);
    cpa_scatter<<<NEDGE / 256, 256, 0, stream>>>(ei, cursor, keys);
    cpa_sortrows<<<N_NODES / 4, 256, 0, stream>>>(rowptr, keys);
    cpa_flash<<<dim3(N_NODES / BR, SPLITS), 256, 0, stream>>>(Xbf, Ybt, es, keys, rowptr,
                                                              msplit, lsplit, Opart);
    cpa_merge<<<N_NODES * DX / 256, 256, 0, stream>>>(msplit, lsplit, Opart, out);
}

// Round 9
// 216.417 us; speedup vs baseline: 2.7985x; 2.3649x over previous
//
#include <hip/hip_runtime.h>
#include <hip/hip_bf16.h>
#include <cstdint>

#define N_NODES 8192
#define DDIM    64
#define DX      128
#define NEDGE   262144
#define BR      128                       // query rows per block (8 waves x 16)
#define BC      64                        // key/value columns per tile
#define SPLITS  8
#define TILES   (N_NODES / BC / SPLITS)   // 16 (compile-time)

typedef float f32x4 __attribute__((ext_vector_type(4)));
typedef short short8 __attribute__((ext_vector_type(8)));

__device__ __forceinline__ short f2bf(float f) {
    union { float f; uint32_t u; } v; v.f = f;
    uint32_t u = v.u;
    uint32_t r = (u + 0x7FFFu + ((u >> 16) & 1u)) >> 16;
    return (short)r;
}
__device__ __forceinline__ float bf2f(short s) {
    union { uint32_t u; float f; } v;
    v.u = ((uint32_t)(uint16_t)s) << 16;
    return v.f;
}

// ---- prep: X = [mag*cos(phase) | mag*sin(phase)] as bf16 [N][128]
__global__ void cpa_prep_x(const float* __restrict__ mag, const float* __restrict__ phase,
                           short* __restrict__ Xbf) {
    int idx = blockIdx.x * 256 + threadIdx.x;      // N*64 threads
    int i = idx >> 6, d = idx & 63;
    float m = mag[idx], p = phase[idx];
    Xbf[i * DX + d]        = f2bf(m * __cosf(p));
    Xbf[i * DX + 64 + d]   = f2bf(m * __sinf(p));
}

// ---- prep: Ybt[c][i] = bf16(Y[i][c]), Y = [mag | phase]  (K-transposed V)
__global__ void cpa_prep_yt(const float* __restrict__ mag, const float* __restrict__ phase,
                            short* __restrict__ Ybt) {
    __shared__ short tile[64][65];
    int bi = blockIdx.x >> 1;
    int bc = blockIdx.x & 1;
    int i0 = bi * 64;
    const float* src = bc ? phase : mag;
    int tid = threadIdx.x;
    for (int itr = 0; itr < 16; ++itr) {
        int idx = tid + itr * 256;                 // 0..4095
        int ii = idx >> 6, cc = idx & 63;
        tile[ii][cc] = f2bf(src[(size_t)(i0 + ii) * 64 + cc]);
    }
    __syncthreads();
    for (int itr = 0; itr < 16; ++itr) {
        int idx = tid + itr * 256;
        int cc = idx >> 6, ii = idx & 63;
        Ybt[(size_t)(bc * 64 + cc) * N_NODES + i0 + ii] = tile[ii][cc];
    }
}

// ---- prep: wsum[k] = sum_h W[h][k], bsum = sum b   (rank-1 collapse of edge Linear)
__global__ void cpa_prep_w(const float* __restrict__ W, const float* __restrict__ b,
                           float* __restrict__ wsb) {
    int t = threadIdx.x;   // 64 threads = 1 wave
    float w0 = W[t * 4 + 0], w1 = W[t * 4 + 1], w2 = W[t * 4 + 2], w3 = W[t * 4 + 3];
    float bb = b[t];
    #pragma unroll
    for (int o = 32; o > 0; o >>= 1) {
        w0 += __shfl_down(w0, o);
        w1 += __shfl_down(w1, o);
        w2 += __shfl_down(w2, o);
        w3 += __shfl_down(w3, o);
        bb += __shfl_down(bb, o);
    }
    if (t == 0) { wsb[0] = w0; wsb[1] = w1; wsb[2] = w2; wsb[3] = w3; wsb[4] = bb; }
}

// ---- edge scores + per-src histogram
__global__ void cpa_edges(const int* __restrict__ ei, const float* __restrict__ ea,
                          const float* __restrict__ wsb, float* __restrict__ es,
                          int* __restrict__ cnt) {
    int e = blockIdx.x * 256 + threadIdx.x;
    float4 a = *(const float4*)(ea + (size_t)e * 4);
    es[e] = a.x * wsb[0] + a.y * wsb[1] + a.z * wsb[2] + a.w * wsb[3] + wsb[4];
    int src = ei[e];
    atomicAdd(&cnt[src], 1);
}

// ---- exclusive scan of 8192 counts (1 block, Hillis-Steele over 256 partials)
__global__ void cpa_scan(const int* __restrict__ cnt, int* __restrict__ rowptr,
                         int* __restrict__ cursor) {
    __shared__ int part[256];
    int t = threadIdx.x;
    int base = t * 32;
    int s = 0;
    for (int k = 0; k < 32; ++k) s += cnt[base + k];
    part[t] = s;
    __syncthreads();
    #pragma unroll
    for (int off = 1; off < 256; off <<= 1) {
        int v = (t >= off) ? part[t - off] : 0;
        __syncthreads();
        part[t] += v;
        __syncthreads();
    }
    if (t == 255) rowptr[N_NODES] = part[255];
    int run = part[t] - s;     // exclusive prefix of this 32-chunk
    for (int k = 0; k < 32; ++k) {
        rowptr[base + k] = run;
        cursor[base + k] = run;
        run += cnt[base + k];
    }
}

// ---- scatter edges into CSR, key = (dst<<18)|e  (sortable by (dst, e))
__global__ void cpa_scatter(const int* __restrict__ ei, int* __restrict__ cursor,
                            int* __restrict__ keys) {
    int e = blockIdx.x * 256 + threadIdx.x;
    int src = ei[e];
    int dst = ei[NEDGE + e];
    int pos = atomicAdd(&cursor[src], 1);
    keys[pos] = (dst << 18) | e;
}

// ---- per-row sort by (dst,e) via wave-parallel bitonic (2 keys/lane, len<=128);
// mark all-but-last duplicate dst dead (numpy last-wins). No scratch, no LDS.
__global__ __launch_bounds__(256) void cpa_sortrows(const int* __restrict__ rowptr,
                                                    int* __restrict__ keys) {
    int row  = blockIdx.x * 4 + (threadIdx.x >> 6);   // one wave per row
    int lane = threadIdx.x & 63;
    int beg = rowptr[row], end = rowptr[row + 1];
    int len = end - beg;
    if (len > 128) len = 128;   // Poisson(32): impossible in practice
    const int idx0 = lane * 2, idx1 = lane * 2 + 1;
    int v0 = (idx0 < len) ? keys[beg + idx0] : 0x7FFFFFFF;
    int v1 = (idx1 < len) ? keys[beg + idx1] : 0x7FFFFFFF;

    #pragma unroll
    for (int k = 2; k <= 128; k <<= 1) {
        #pragma unroll
        for (int j = k >> 1; j >= 2; j >>= 1) {
            int ldist = j >> 1;                        // partner lane distance
            int p0 = __shfl_xor(v0, ldist);
            int p1 = __shfl_xor(v1, ldist);
            bool asc = (idx0 & k) == 0;                // same for both slots (k>=2)
            bool low = (idx0 & j) == 0;                // same for both slots (j>=2)
            int n0 = (low == asc) ? min(v0, p0) : max(v0, p0);
            int n1 = (low == asc) ? min(v1, p1) : max(v1, p1);
            v0 = n0; v1 = n1;
        }
        {   // j == 1: within-lane compare of the two slots
            bool asc = (idx0 & k) == 0;
            int lo = min(v0, v1), hi = max(v0, v1);
            v0 = asc ? lo : hi;
            v1 = asc ? hi : lo;
        }
    }

    // mark dead: element idx is dead iff idx+1 < len and dst(idx+1)==dst(idx).
    int nextv0 = __shfl_down(v0, 1);                   // lane+1's v0 = element idx1+1
    bool dead0 = (idx0 + 1 < len) && ((v0 >> 18) == (v1 >> 18));
    bool dead1 = (idx1 + 1 < len) && ((v1 >> 18) == (nextv0 >> 18));
    if (idx0 < len) keys[beg + idx0] = v0 | (dead0 ? 0x80000000 : 0);
    if (idx1 < len) keys[beg + idx1] = v1 | (dead1 ? 0x80000000 : 0);
}

// ---- flash attention: R4-verbatim inner loop, but 512-thread blocks covering
// BR=128 query rows (8 waves x 16 rows). Same BC=64 tile, 4 barriers/tile,
// in-loop serial bias walker. LDS ~54.5 KB -> still 2 blocks/CU, but 16
// waves/CU (2x R4 TLP); staging amortized over 2x rows. Grid 64x8 = 512 =
// exactly 2 blocks/CU, one generation.
__global__ __launch_bounds__(512) void cpa_flash(
    const short* __restrict__ Xbf, const short* __restrict__ Ybt,
    const float* __restrict__ es, const int* __restrict__ keys,
    const int* __restrict__ rowptr,
    float* __restrict__ msplit, float* __restrict__ lsplit,
    short* __restrict__ Opart)
{
    __shared__ short Xj[BC][136];     // X tile (j rows), stride 136 (16B-aligned rows)
    __shared__ short Yt[DX][72];      // V tile K-transposed: Yt[feature][j-local]
    __shared__ short Pl[BR][72];      // P tile bf16 (C-layout -> A-layout round trip)
    __shared__ int   cur[BR];
    __shared__ int   rend_s[BR];
    __shared__ float dls[BR];

    const int tid   = threadIdx.x;
    const int lane  = tid & 63;
    const int w     = tid >> 6;       // wave 0..7 -> rows 16w..16w+15
    const int q     = lane >> 4;      // quad
    const int colid = lane & 15;

    const int ib = blockIdx.x;        // 0..63
    const int split = blockIdx.y;     // 0..SPLITS-1
    const int i0 = ib * BR;
    const int jstart = split * (N_NODES / SPLITS);

    // A-fragments straight from global (16B contiguous along features, one-time)
    short8 afrag[4];
    #pragma unroll
    for (int kf = 0; kf < 4; ++kf)
        afrag[kf] = *(const short8*)(Xbf + (size_t)(i0 + w * 16 + colid) * DX + kf * 32 + q * 8);

    if (tid < BR) {
        int i = i0 + tid;
        int c = rowptr[i], e_ = rowptr[i + 1];
        while (c < e_) {
            int k = keys[c];
            int dst = (k >> 18) & 0x1FFF;
            if (dst >= jstart) break;
            ++c;
        }
        cur[tid] = c; rend_s[tid] = e_;
        dls[tid] = 0.f;
    }
    __syncthreads();

    float m_r[4] = {-1e30f, -1e30f, -1e30f, -1e30f};
    float l_r[4] = {0.f, 0.f, 0.f, 0.f};
    f32x4 O[8];
    #pragma unroll
    for (int t = 0; t < 8; ++t) O[t] = (f32x4){0.f, 0.f, 0.f, 0.f};

    for (int tt = 0; tt < TILES; ++tt) {
        const int j0 = jstart + tt * BC;
        // phase A: stage X_j and Y_t tiles (cooperative, vectorized, 512 threads)
        for (int itr = 0; itr < 2; ++itr) {
            int idx = tid + itr * 512;            // 0..1023
            int r = idx >> 4;                     // 0..63
            int c8 = (idx & 15) << 3;
            *(int4*)(&Xj[r][c8]) = *(const int4*)(Xbf + (size_t)(j0 + r) * DX + c8);
        }
        for (int itr = 0; itr < 2; ++itr) {
            int idx = tid + itr * 512;            // 0..1023
            int n = idx >> 3;                     // 0..127
            int k8 = (idx & 7) << 3;
            *(int4*)(&Yt[n][k8]) = *(const int4*)(Ybt + (size_t)n * N_NODES + j0 + k8);
        }
        __syncthreads();  // B1

        // phase B: S = Xi·Xj^T (wave w: rows 16w..16w+15, cols 0..63)
        f32x4 S[4];
        #pragma unroll
        for (int st = 0; st < 4; ++st) {
            f32x4 acc = (f32x4){0.f, 0.f, 0.f, 0.f};
            #pragma unroll
            for (int kf = 0; kf < 4; ++kf) {
                short8 bfrag = *(const short8*)&Xj[st * 16 + colid][kf * 32 + q * 8];
                acc = __builtin_amdgcn_mfma_f32_16x16x32_bf16(afrag[kf], bfrag, acc, 0, 0, 0);
            }
            S[st] = acc;
        }
        // online softmax (C-layout: row = q*4+r local-16, col = st*16+colid)
        float mnew[4], alpha[4];
        #pragma unroll
        for (int r = 0; r < 4; ++r) {
            float mx = fmaxf(fmaxf(S[0][r], S[1][r]), fmaxf(S[2][r], S[3][r]));
            mx = fmaxf(mx, __shfl_xor(mx, 1));
            mx = fmaxf(mx, __shfl_xor(mx, 2));
            mx = fmaxf(mx, __shfl_xor(mx, 4));
            mx = fmaxf(mx, __shfl_xor(mx, 8));
            mnew[r] = fmaxf(m_r[r], mx);
            alpha[r] = __expf(m_r[r] - mnew[r]);
            m_r[r] = mnew[r];
        }
        float rsum[4] = {0.f, 0.f, 0.f, 0.f};
        short pb[4][4];
        #pragma unroll
        for (int st = 0; st < 4; ++st) {
            #pragma unroll
            for (int r = 0; r < 4; ++r) {
                float p = __expf(S[st][r] - mnew[r]);
                rsum[r] += p;
                pb[st][r] = f2bf(p);
            }
        }
        #pragma unroll
        for (int r = 0; r < 4; ++r) {
            float s_ = rsum[r];
            s_ += __shfl_xor(s_, 1);
            s_ += __shfl_xor(s_, 2);
            s_ += __shfl_xor(s_, 4);
            s_ += __shfl_xor(s_, 8);
            l_r[r] = l_r[r] * alpha[r] + s_;
            #pragma unroll
            for (int t = 0; t < 8; ++t) O[t][r] *= alpha[r];
        }
        // phase C: P -> LDS (bf16)
        #pragma unroll
        for (int st = 0; st < 4; ++st)
            #pragma unroll
            for (int r = 0; r < 4; ++r)
                Pl[w * 16 + q * 4 + r][st * 16 + colid] = pb[st][r];
        __syncthreads();  // B3

        // phase C2: sparse bias: P *= exp(bias) at live edges; track Δl per row
        if (tid < BR) {
            int c = cur[tid];
            const int e_ = rend_s[tid];
            const int jend = j0 + BC;
            float dlocal = 0.f;
            while (c < e_) {
                int k = keys[c];
                int dst = (k >> 18) & 0x1FFF;
                if (dst >= jend) break;
                ++c;
                if (k >= 0) {  // live (last duplicate wins)
                    int ec = dst - j0;
                    float old = bf2f(Pl[tid][ec]);
                    float nw = old * __expf(es[k & 0x3FFFF]);
                    Pl[tid][ec] = f2bf(nw);
                    dlocal += nw - old;
                }
            }
            cur[tid] = c;
            dls[tid] = dlocal;
        }
        __syncthreads();  // B3.5

        // phase D: l += Δl; O += P·Y
        #pragma unroll
        for (int r = 0; r < 4; ++r)
            l_r[r] += dls[w * 16 + q * 4 + r];

        short8 pf0 = *(const short8*)&Pl[w * 16 + colid][q * 8];
        short8 pf1 = *(const short8*)&Pl[w * 16 + colid][32 + q * 8];
        #pragma unroll
        for (int t = 0; t < 8; ++t) {
            short8 b0 = *(const short8*)&Yt[t * 16 + colid][q * 8];
            short8 b1 = *(const short8*)&Yt[t * 16 + colid][32 + q * 8];
            O[t] = __builtin_amdgcn_mfma_f32_16x16x32_bf16(pf0, b0, O[t], 0, 0, 0);
            O[t] = __builtin_amdgcn_mfma_f32_16x16x32_bf16(pf1, b1, O[t], 0, 0, 0);
        }
        __syncthreads();  // B4 (protect tiles for next iteration)
    }

    // epilogue: store partial m, l, O (O as bf16)
    const int ibase = i0 + w * 16 + q * 4;
    #pragma unroll
    for (int r = 0; r < 4; ++r) {
        if (colid == r) {
            msplit[(size_t)split * N_NODES + ibase + r] = m_r[r];
            lsplit[(size_t)split * N_NODES + ibase + r] = l_r[r];
        }
    }
    #pragma unroll
    for (int t = 0; t < 8; ++t) {
        #pragma unroll
        for (int r = 0; r < 4; ++r) {
            size_t off = ((size_t)split * N_NODES + ibase + r) * DX + t * 16 + colid;
            Opart[off] = f2bf(O[t][r]);
        }
    }
}

// ---- merge splits + normalize + write [new_mag | new_phase]
__global__ void cpa_merge(const float* __restrict__ msplit, const float* __restrict__ lsplit,
                          const short* __restrict__ Opart, float* __restrict__ out) {
    int gid = blockIdx.x * 256 + threadIdx.x;   // N*128 threads
    int i = gid >> 7;
    int c = gid & 127;
    float mm = -1e30f;
    #pragma unroll
    for (int s = 0; s < SPLITS; ++s) mm = fmaxf(mm, msplit[(size_t)s * N_NODES + i]);
    float den = 0.f, num = 0.f;
    #pragma unroll
    for (int s = 0; s < SPLITS; ++s) {
        float wgt = __expf(msplit[(size_t)s * N_NODES + i] - mm);
        den += lsplit[(size_t)s * N_NODES + i] * wgt;
        num += bf2f(Opart[((size_t)s * N_NODES + i) * DX + c]) * wgt;
    }
    float val = num / den;
    if (c < 64) out[(size_t)i * 64 + c] = val;
    else        out[(size_t)N_NODES * 64 + (size_t)i * 64 + (c - 64)] = val;
}

extern "C" void kernel_launch(void* const* d_in, const int* in_sizes, int n_in,
                              void* d_out, int out_size, void* d_ws, size_t ws_size,
                              hipStream_t stream)
{
    const float* mag   = (const float*)d_in[0];
    const float* phase = (const float*)d_in[1];
    const int*   ei    = (const int*)d_in[2];     // edge_index [2][E] (int32 per harness)
    const float* ea    = (const float*)d_in[3];
    const float* W     = (const float*)d_in[4];
    const float* b     = (const float*)d_in[5];
    float* out = (float*)d_out;

    char* ws = (char*)d_ws;
    short* Xbf    = (short*)(ws + 0);               // 2 MB
    short* Ybt    = (short*)(ws + 2097152);         // 2 MB
    float* es     = (float*)(ws + 4194304);         // 1 MB
    int*   keys   = (int*)  (ws + 5242880);         // 1 MB
    int*   rowptr = (int*)  (ws + 6291456);         // 36 KB slot
    int*   cnt    = (int*)  (ws + 6328320);         // 32 KB
    int*   cursor = (int*)  (ws + 6361088);         // 32 KB
    float* wsb    = (float*)(ws + 6393856);         // 256 B
    float* msplit = (float*)(ws + 6394112);         // 256 KB (8 splits)
    float* lsplit = (float*)(ws + 6656256);         // 256 KB
    short* Opart  = (short*)(ws + 6918400);         // 16 MB (bf16, 8 splits)

    hipMemsetAsync(cnt, 0, N_NODES * sizeof(int), stream);
    cpa_prep_x<<<N_NODES * DDIM / 256, 256, 0, stream>>>(mag, phase, Xbf);
    cpa_prep_yt<<<(N_NODES / 64) * 2, 256, 0, stream>>>(mag, phase, Ybt);
    cpa_prep_w<<<1, 64, 0, stream>>>(W, b, wsb);
    cpa_edges<<<NEDGE / 256, 256, 0, stream>>>(ei, ea, wsb, es, cnt);
    cpa_scan<<<1, 256, 0, stream>>>(cnt, rowptr, cursor);
    cpa_scatter<<<NEDGE / 256, 256, 0, stream>>>(ei, cursor, keys);
    cpa_sortrows<<<N_NODES / 4, 256, 0, stream>>>(rowptr, keys);
    cpa_flash<<<dim3(N_NODES / BR, SPLITS), 512, 0, stream>>>(Xbf, Ybt, es, keys, rowptr,
                                                              msplit, lsplit, Opart);
    cpa_merge<<<N_NODES * DX / 256, 256, 0, stream>>>(msplit, lsplit, Opart, out);
}

// Round 10
// 207.191 us; speedup vs baseline: 2.9231x; 1.0445x over previous
//
#include <hip/hip_runtime.h>
#include <hip/hip_bf16.h>
#include <cstdint>

#define N_NODES 8192
#define DDIM    64
#define DX      128
#define NEDGE   262144
#define BR      128                       // query rows per block (8 waves x 16)
#define BC      64                        // key/value columns per tile
#define SPLITS  8
#define TILES   (N_NODES / BC / SPLITS)   // 16 (compile-time)

typedef float f32x4 __attribute__((ext_vector_type(4)));
typedef short short8 __attribute__((ext_vector_type(8)));

__device__ __forceinline__ short f2bf(float f) {
    union { float f; uint32_t u; } v; v.f = f;
    uint32_t u = v.u;
    uint32_t r = (u + 0x7FFFu + ((u >> 16) & 1u)) >> 16;
    return (short)r;
}
__device__ __forceinline__ float bf2f(short s) {
    union { uint32_t u; float f; } v;
    v.u = ((uint32_t)(uint16_t)s) << 16;
    return v.f;
}

// ---- prep: wsum[k] = sum_h W[h][k], bsum = sum b   (rank-1 collapse of edge Linear)
// Must run BEFORE cpa_prep_all (edges section reads wsb).
__global__ void cpa_prep_w(const float* __restrict__ W, const float* __restrict__ b,
                           float* __restrict__ wsb) {
    int t = threadIdx.x;   // 64 threads = 1 wave
    float w0 = W[t * 4 + 0], w1 = W[t * 4 + 1], w2 = W[t * 4 + 2], w3 = W[t * 4 + 3];
    float bb = b[t];
    #pragma unroll
    for (int o = 32; o > 0; o >>= 1) {
        w0 += __shfl_down(w0, o);
        w1 += __shfl_down(w1, o);
        w2 += __shfl_down(w2, o);
        w3 += __shfl_down(w3, o);
        bb += __shfl_down(bb, o);
    }
    if (t == 0) { wsb[0] = w0; wsb[1] = w1; wsb[2] = w2; wsb[3] = w3; wsb[4] = bb; }
}

// ---- fused prep: [0,2048) X-build, [2048,2304) Y-transpose, [2304,3328) edges
__global__ void cpa_prep_all(const float* __restrict__ mag, const float* __restrict__ phase,
                             const int* __restrict__ ei, const float* __restrict__ ea,
                             const float* __restrict__ wsb,
                             short* __restrict__ Xbf, short* __restrict__ Ybt,
                             float* __restrict__ es, int* __restrict__ cnt) {
    __shared__ short tile[64][65];
    const int blk = blockIdx.x;
    const int tid = threadIdx.x;
    if (blk < 2048) {
        // X = [mag*cos(phase) | mag*sin(phase)] bf16 [N][128]
        int idx = blk * 256 + tid;                 // N*64 threads
        int i = idx >> 6, d = idx & 63;
        float m = mag[idx], p = phase[idx];
        Xbf[i * DX + d]      = f2bf(m * __cosf(p));
        Xbf[i * DX + 64 + d] = f2bf(m * __sinf(p));
    } else if (blk < 2304) {
        // Ybt[c][i] = bf16(Y[i][c]), Y = [mag | phase]
        int bb = blk - 2048;
        int bi = bb >> 1;
        int bc = bb & 1;
        int i0 = bi * 64;
        const float* src = bc ? phase : mag;
        for (int itr = 0; itr < 16; ++itr) {
            int idx = tid + itr * 256;             // 0..4095
            int ii = idx >> 6, cc = idx & 63;
            tile[ii][cc] = f2bf(src[(size_t)(i0 + ii) * 64 + cc]);
        }
        __syncthreads();
        for (int itr = 0; itr < 16; ++itr) {
            int idx = tid + itr * 256;
            int cc = idx >> 6, ii = idx & 63;
            Ybt[(size_t)(bc * 64 + cc) * N_NODES + i0 + ii] = tile[ii][cc];
        }
    } else {
        // edge scores + per-src histogram
        int e = (blk - 2304) * 256 + tid;
        float4 a = *(const float4*)(ea + (size_t)e * 4);
        es[e] = a.x * wsb[0] + a.y * wsb[1] + a.z * wsb[2] + a.w * wsb[3] + wsb[4];
        int src = ei[e];
        atomicAdd(&cnt[src], 1);
    }
}

// ---- exclusive scan of 8192 counts (1 block, Hillis-Steele over 256 partials)
__global__ void cpa_scan(const int* __restrict__ cnt, int* __restrict__ rowptr,
                         int* __restrict__ cursor) {
    __shared__ int part[256];
    int t = threadIdx.x;
    int base = t * 32;
    int s = 0;
    for (int k = 0; k < 32; ++k) s += cnt[base + k];
    part[t] = s;
    __syncthreads();
    #pragma unroll
    for (int off = 1; off < 256; off <<= 1) {
        int v = (t >= off) ? part[t - off] : 0;
        __syncthreads();
        part[t] += v;
        __syncthreads();
    }
    if (t == 255) rowptr[N_NODES] = part[255];
    int run = part[t] - s;     // exclusive prefix of this 32-chunk
    for (int k = 0; k < 32; ++k) {
        rowptr[base + k] = run;
        cursor[base + k] = run;
        run += cnt[base + k];
    }
}

// ---- scatter edges into CSR, key = (dst<<18)|e  (sortable by (dst, e))
__global__ void cpa_scatter(const int* __restrict__ ei, int* __restrict__ cursor,
                            int* __restrict__ keys) {
    int e = blockIdx.x * 256 + threadIdx.x;
    int src = ei[e];
    int dst = ei[NEDGE + e];
    int pos = atomicAdd(&cursor[src], 1);
    keys[pos] = (dst << 18) | e;
}

// ---- per-row sort by (dst,e) via wave-parallel bitonic (2 keys/lane, len<=128);
// mark all-but-last duplicate dst dead (numpy last-wins). No scratch, no LDS.
__global__ __launch_bounds__(256) void cpa_sortrows(const int* __restrict__ rowptr,
                                                    int* __restrict__ keys) {
    int row  = blockIdx.x * 4 + (threadIdx.x >> 6);   // one wave per row
    int lane = threadIdx.x & 63;
    int beg = rowptr[row], end = rowptr[row + 1];
    int len = end - beg;
    if (len > 128) len = 128;   // Poisson(32): impossible in practice
    const int idx0 = lane * 2, idx1 = lane * 2 + 1;
    int v0 = (idx0 < len) ? keys[beg + idx0] : 0x7FFFFFFF;
    int v1 = (idx1 < len) ? keys[beg + idx1] : 0x7FFFFFFF;

    #pragma unroll
    for (int k = 2; k <= 128; k <<= 1) {
        #pragma unroll
        for (int j = k >> 1; j >= 2; j >>= 1) {
            int ldist = j >> 1;                        // partner lane distance
            int p0 = __shfl_xor(v0, ldist);
            int p1 = __shfl_xor(v1, ldist);
            bool asc = (idx0 & k) == 0;                // same for both slots (k>=2)
            bool low = (idx0 & j) == 0;                // same for both slots (j>=2)
            int n0 = (low == asc) ? min(v0, p0) : max(v0, p0);
            int n1 = (low == asc) ? min(v1, p1) : max(v1, p1);
            v0 = n0; v1 = n1;
        }
        {   // j == 1: within-lane compare of the two slots
            bool asc = (idx0 & k) == 0;
            int lo = min(v0, v1), hi = max(v0, v1);
            v0 = asc ? lo : hi;
            v1 = asc ? hi : lo;
        }
    }

    // mark dead: element idx is dead iff idx+1 < len and dst(idx+1)==dst(idx).
    int nextv0 = __shfl_down(v0, 1);                   // lane+1's v0 = element idx1+1
    bool dead0 = (idx0 + 1 < len) && ((v0 >> 18) == (v1 >> 18));
    bool dead1 = (idx1 + 1 < len) && ((v1 >> 18) == (nextv0 >> 18));
    if (idx0 < len) keys[beg + idx0] = v0 | (dead0 ? 0x80000000 : 0);
    if (idx1 < len) keys[beg + idx1] = v1 | (dead1 ? 0x80000000 : 0);
}

// ---- flash attention: R9 structure (512 threads, BR=128, BC=64) but the bias
// walker is distributed per-wave (lanes 0..15 of wave w walk rows 16w..16w+15).
// The whole Pl write -> bias RMW -> read chain is same-wave DS (in-order pipe),
// so B3/B3.5 are deleted: 2 barriers/tile. Delta-l moves by shuffle, not LDS.
__global__ __launch_bounds__(512) void cpa_flash(
    const short* __restrict__ Xbf, const short* __restrict__ Ybt,
    const float* __restrict__ es, const int* __restrict__ keys,
    const int* __restrict__ rowptr,
    float* __restrict__ msplit, float* __restrict__ lsplit,
    short* __restrict__ Opart)
{
    __shared__ short Xj[BC][136];     // X tile (j rows), stride 136 (16B-aligned rows)
    __shared__ short Yt[DX][72];      // V tile K-transposed: Yt[feature][j-local]
    __shared__ short Pl[BR][72];      // P tile bf16; wave w touches rows 16w..16w+15 only

    const int tid   = threadIdx.x;
    const int lane  = tid & 63;
    const int w     = tid >> 6;       // wave 0..7 -> rows 16w..16w+15
    const int q     = lane >> 4;      // quad
    const int colid = lane & 15;

    const int ib = blockIdx.x;        // 0..63
    const int split = blockIdx.y;     // 0..SPLITS-1
    const int i0 = ib * BR;
    const int jstart = split * (N_NODES / SPLITS);

    // A-fragments straight from global (16B contiguous along features, one-time)
    short8 afrag[4];
    #pragma unroll
    for (int kf = 0; kf < 4; ++kf)
        afrag[kf] = *(const short8*)(Xbf + (size_t)(i0 + w * 16 + colid) * DX + kf * 32 + q * 8);

    // per-wave walker state: lane<16 owns row i0 + w*16 + lane
    int cur = 0, rend = 0;
    if (lane < 16) {
        int i = i0 + w * 16 + lane;
        cur = rowptr[i]; rend = rowptr[i + 1];
        while (cur < rend) {
            int k = keys[cur];
            int dst = (k >> 18) & 0x1FFF;
            if (dst >= jstart) break;
            ++cur;
        }
    }

    float m_r[4] = {-1e30f, -1e30f, -1e30f, -1e30f};
    float l_r[4] = {0.f, 0.f, 0.f, 0.f};
    f32x4 O[8];
    #pragma unroll
    for (int t = 0; t < 8; ++t) O[t] = (f32x4){0.f, 0.f, 0.f, 0.f};

    for (int tt = 0; tt < TILES; ++tt) {
        const int j0 = jstart + tt * BC;
        // phase A: stage X_j and Y_t tiles (cooperative, vectorized, 512 threads)
        for (int itr = 0; itr < 2; ++itr) {
            int idx = tid + itr * 512;            // 0..1023
            int r = idx >> 4;                     // 0..63
            int c8 = (idx & 15) << 3;
            *(int4*)(&Xj[r][c8]) = *(const int4*)(Xbf + (size_t)(j0 + r) * DX + c8);
        }
        for (int itr = 0; itr < 2; ++itr) {
            int idx = tid + itr * 512;            // 0..1023
            int n = idx >> 3;                     // 0..127
            int k8 = (idx & 7) << 3;
            *(int4*)(&Yt[n][k8]) = *(const int4*)(Ybt + (size_t)n * N_NODES + j0 + k8);
        }
        __syncthreads();  // B1

        // phase B: S = Xi·Xj^T (wave w: rows 16w..16w+15, cols 0..63)
        f32x4 S[4];
        #pragma unroll
        for (int st = 0; st < 4; ++st) {
            f32x4 acc = (f32x4){0.f, 0.f, 0.f, 0.f};
            #pragma unroll
            for (int kf = 0; kf < 4; ++kf) {
                short8 bfrag = *(const short8*)&Xj[st * 16 + colid][kf * 32 + q * 8];
                acc = __builtin_amdgcn_mfma_f32_16x16x32_bf16(afrag[kf], bfrag, acc, 0, 0, 0);
            }
            S[st] = acc;
        }
        // online softmax (C-layout: row = q*4+r local-16, col = st*16+colid)
        float mnew[4], alpha[4];
        #pragma unroll
        for (int r = 0; r < 4; ++r) {
            float mx = fmaxf(fmaxf(S[0][r], S[1][r]), fmaxf(S[2][r], S[3][r]));
            mx = fmaxf(mx, __shfl_xor(mx, 1));
            mx = fmaxf(mx, __shfl_xor(mx, 2));
            mx = fmaxf(mx, __shfl_xor(mx, 4));
            mx = fmaxf(mx, __shfl_xor(mx, 8));
            mnew[r] = fmaxf(m_r[r], mx);
            alpha[r] = __expf(m_r[r] - mnew[r]);
            m_r[r] = mnew[r];
        }
        float rsum[4] = {0.f, 0.f, 0.f, 0.f};
        short pb[4][4];
        #pragma unroll
        for (int st = 0; st < 4; ++st) {
            #pragma unroll
            for (int r = 0; r < 4; ++r) {
                float p = __expf(S[st][r] - mnew[r]);
                rsum[r] += p;
                pb[st][r] = f2bf(p);
            }
        }
        #pragma unroll
        for (int r = 0; r < 4; ++r) {
            float s_ = rsum[r];
            s_ += __shfl_xor(s_, 1);
            s_ += __shfl_xor(s_, 2);
            s_ += __shfl_xor(s_, 4);
            s_ += __shfl_xor(s_, 8);
            l_r[r] = l_r[r] * alpha[r] + s_;
            #pragma unroll
            for (int t = 0; t < 8; ++t) O[t][r] *= alpha[r];
        }
        // phase C: P -> LDS (bf16) — own-wave rows only
        #pragma unroll
        for (int st = 0; st < 4; ++st)
            #pragma unroll
            for (int r = 0; r < 4; ++r)
                Pl[w * 16 + q * 4 + r][st * 16 + colid] = pb[st][r];

        // phase C2 (per-wave): lanes 0..15 bias-walk their own row; same-wave DS
        // ordering makes write->RMW->read safe without barriers.
        float dlocal = 0.f;
        if (lane < 16) {
            const int jend = j0 + BC;
            int c = cur;
            while (c < rend) {
                int k = keys[c];
                int dst = (k >> 18) & 0x1FFF;
                if (dst >= jend) break;
                ++c;
                if (k >= 0) {  // live (last duplicate wins)
                    int ec = dst - j0;
                    float old = bf2f(Pl[w * 16 + lane][ec]);
                    float nw = old * __expf(es[k & 0x3FFFF]);
                    Pl[w * 16 + lane][ec] = f2bf(nw);
                    dlocal += nw - old;
                }
            }
            cur = c;
        }
        // phase D: l += Δl (shuffle from owner lane); O += P·Y
        #pragma unroll
        for (int r = 0; r < 4; ++r)
            l_r[r] += __shfl(dlocal, q * 4 + r);

        short8 pf0 = *(const short8*)&Pl[w * 16 + colid][q * 8];
        short8 pf1 = *(const short8*)&Pl[w * 16 + colid][32 + q * 8];
        #pragma unroll
        for (int t = 0; t < 8; ++t) {
            short8 b0 = *(const short8*)&Yt[t * 16 + colid][q * 8];
            short8 b1 = *(const short8*)&Yt[t * 16 + colid][32 + q * 8];
            O[t] = __builtin_amdgcn_mfma_f32_16x16x32_bf16(pf0, b0, O[t], 0, 0, 0);
            O[t] = __builtin_amdgcn_mfma_f32_16x16x32_bf16(pf1, b1, O[t], 0, 0, 0);
        }
        __syncthreads();  // B4 (WAR: protect Xj/Yt for next iteration)
    }

    // epilogue: store partial m, l, O (O as bf16)
    const int ibase = i0 + w * 16 + q * 4;
    #pragma unroll
    for (int r = 0; r < 4; ++r) {
        if (colid == r) {
            msplit[(size_t)split * N_NODES + ibase + r] = m_r[r];
            lsplit[(size_t)split * N_NODES + ibase + r] = l_r[r];
        }
    }
    #pragma unroll
    for (int t = 0; t < 8; ++t) {
        #pragma unroll
        for (int r = 0; r < 4; ++r) {
            size_t off = ((size_t)split * N_NODES + ibase + r) * DX + t * 16 + colid;
            Opart[off] = f2bf(O[t][r]);
        }
    }
}

// ---- merge splits + normalize + write [new_mag | new_phase]
__global__ void cpa_merge(const float* __restrict__ msplit, const float* __restrict__ lsplit,
                          const short* __restrict__ Opart, float* __restrict__ out) {
    int gid = blockIdx.x * 256 + threadIdx.x;   // N*128 threads
    int i = gid >> 7;
    int c = gid & 127;
    float mm = -1e30f;
    #pragma unroll
    for (int s = 0; s < SPLITS; ++s) mm = fmaxf(mm, msplit[(size_t)s * N_NODES + i]);
    float den = 0.f, num = 0.f;
    #pragma unroll
    for (int s = 0; s < SPLITS; ++s) {
        float wgt = __expf(msplit[(size_t)s * N_NODES + i] - mm);
        den += lsplit[(size_t)s * N_NODES + i] * wgt;
        num += bf2f(Opart[((size_t)s * N_NODES + i) * DX + c]) * wgt;
    }
    float val = num / den;
    if (c < 64) out[(size_t)i * 64 + c] = val;
    else        out[(size_t)N_NODES * 64 + (size_t)i * 64 + (c - 64)] = val;
}

extern "C" void kernel_launch(void* const* d_in, const int* in_sizes, int n_in,
                              void* d_out, int out_size, void* d_ws, size_t ws_size,
                              hipStream_t stream)
{
    const float* mag   = (const float*)d_in[0];
    const float* phase = (const float*)d_in[1];
    const int*   ei    = (const int*)d_in[2];     // edge_index [2][E] (int32 per harness)
    const float* ea    = (const float*)d_in[3];
    const float* W     = (const float*)d_in[4];
    const float* b     = (const float*)d_in[5];
    float* out = (float*)d_out;

    char* ws = (char*)d_ws;
    short* Xbf    = (short*)(ws + 0);               // 2 MB
    short* Ybt    = (short*)(ws + 2097152);         // 2 MB
    float* es     = (float*)(ws + 4194304);         // 1 MB
    int*   keys   = (int*)  (ws + 5242880);         // 1 MB
    int*   rowptr = (int*)  (ws + 6291456);         // 36 KB slot
    int*   cnt    = (int*)  (ws + 6328320);         // 32 KB
    int*   cursor = (int*)  (ws + 6361088);         // 32 KB
    float* wsb    = (float*)(ws + 6393856);         // 256 B
    float* msplit = (float*)(ws + 6394112);         // 256 KB (8 splits)
    float* lsplit = (float*)(ws + 6656256);         // 256 KB
    short* Opart  = (short*)(ws + 6918400);         // 16 MB (bf16, 8 splits)

    hipMemsetAsync(cnt, 0, N_NODES * sizeof(int), stream);
    cpa_prep_w<<<1, 64, 0, stream>>>(W, b, wsb);
    cpa_prep_all<<<2048 + 256 + NEDGE / 256, 256, 0, stream>>>(mag, phase, ei, ea, wsb,
                                                               Xbf, Ybt, es, cnt);
    cpa_scan<<<1, 256, 0, stream>>>(cnt, rowptr, cursor);
    cpa_scatter<<<NEDGE / 256, 256, 0, stream>>>(ei, cursor, keys);
    cpa_sortrows<<<N_NODES / 4, 256, 0, stream>>>(rowptr, keys);
    cpa_flash<<<dim3(N_NODES / BR, SPLITS), 512, 0, stream>>>(Xbf, Ybt, es, keys, rowptr,
                                                              msplit, lsplit, Opart);
    cpa_merge<<<N_NODES * DX / 256, 256, 0, stream>>>(msplit, lsplit, Opart, out);
}

// Round 11
// 178.522 us; speedup vs baseline: 3.3925x; 1.1606x over previous
//
#include <hip/hip_runtime.h>
#include <hip/hip_bf16.h>
#include <cstdint>

#define N_NODES 8192
#define DDIM    64
#define DX      128
#define NEDGE   262144
#define BR      128                       // query rows per block (8 waves x 16)
#define BC      64                        // key/value columns per tile
#define SPLITS  8
#define TILES   (N_NODES / BC / SPLITS)   // 16 (compile-time)
#define RCAP    64                        // per-row edge bin capacity (Poisson(32), 5.7 sigma)
#define MSHIFT  66.0f                     // fixed softmax shift: scores < 64 always

typedef float f32x4 __attribute__((ext_vector_type(4)));
typedef short short8 __attribute__((ext_vector_type(8)));

__device__ __forceinline__ short f2bf(float f) {
    union { float f; uint32_t u; } v; v.f = f;
    uint32_t u = v.u;
    uint32_t r = (u + 0x7FFFu + ((u >> 16) & 1u)) >> 16;
    return (short)r;
}
__device__ __forceinline__ float bf2f(short s) {
    union { uint32_t u; float f; } v;
    v.u = ((uint32_t)(uint16_t)s) << 16;
    return v.f;
}

// ---- prep: wsum[k] = sum_h W[h][k], bsum = sum b   (rank-1 collapse of edge Linear)
// Must run BEFORE cpa_prep_all (edges section reads wsb).
__global__ void cpa_prep_w(const float* __restrict__ W, const float* __restrict__ b,
                           float* __restrict__ wsb) {
    int t = threadIdx.x;   // 64 threads = 1 wave
    float w0 = W[t * 4 + 0], w1 = W[t * 4 + 1], w2 = W[t * 4 + 2], w3 = W[t * 4 + 3];
    float bb = b[t];
    #pragma unroll
    for (int o = 32; o > 0; o >>= 1) {
        w0 += __shfl_down(w0, o);
        w1 += __shfl_down(w1, o);
        w2 += __shfl_down(w2, o);
        w3 += __shfl_down(w3, o);
        bb += __shfl_down(bb, o);
    }
    if (t == 0) { wsb[0] = w0; wsb[1] = w1; wsb[2] = w2; wsb[3] = w3; wsb[4] = bb; }
}

// ---- fused prep: [0,2048) X-build, [2048,2304) Y-transpose, [2304,3328) edges
// Edges scatter directly into fixed-capacity per-row bins (no scan/scatter pass).
__global__ void cpa_prep_all(const float* __restrict__ mag, const float* __restrict__ phase,
                             const int* __restrict__ ei, const float* __restrict__ ea,
                             const float* __restrict__ wsb,
                             short* __restrict__ Xbf, short* __restrict__ Ybt,
                             float* __restrict__ es, int* __restrict__ cnt,
                             int* __restrict__ keys) {
    __shared__ short tile[64][65];
    const int blk = blockIdx.x;
    const int tid = threadIdx.x;
    if (blk < 2048) {
        // X = [mag*cos(phase) | mag*sin(phase)] bf16 [N][128]
        int idx = blk * 256 + tid;                 // N*64 threads
        int i = idx >> 6, d = idx & 63;
        float m = mag[idx], p = phase[idx];
        Xbf[i * DX + d]      = f2bf(m * __cosf(p));
        Xbf[i * DX + 64 + d] = f2bf(m * __sinf(p));
    } else if (blk < 2304) {
        // Ybt[c][i] = bf16(Y[i][c]), Y = [mag | phase]
        int bb = blk - 2048;
        int bi = bb >> 1;
        int bc = bb & 1;
        int i0 = bi * 64;
        const float* src = bc ? phase : mag;
        for (int itr = 0; itr < 16; ++itr) {
            int idx = tid + itr * 256;             // 0..4095
            int ii = idx >> 6, cc = idx & 63;
            tile[ii][cc] = f2bf(src[(size_t)(i0 + ii) * 64 + cc]);
        }
        __syncthreads();
        for (int itr = 0; itr < 16; ++itr) {
            int idx = tid + itr * 256;
            int cc = idx >> 6, ii = idx & 63;
            Ybt[(size_t)(bc * 64 + cc) * N_NODES + i0 + ii] = tile[ii][cc];
        }
    } else {
        // edge scores + direct CSR binning, key = (dst<<18)|e
        int e = (blk - 2304) * 256 + tid;
        float4 a = *(const float4*)(ea + (size_t)e * 4);
        es[e] = a.x * wsb[0] + a.y * wsb[1] + a.z * wsb[2] + a.w * wsb[3] + wsb[4];
        int src = ei[e];
        int dst = ei[NEDGE + e];
        int pos = atomicAdd(&cnt[src], 1);
        if (pos < RCAP) keys[src * RCAP + pos] = (dst << 18) | e;
    }
}

// ---- per-row sort by (dst,e): one wave per row, 1 key/lane, 64-wide bitonic;
// mark all-but-last duplicate dst dead (numpy last-wins).
__global__ __launch_bounds__(256) void cpa_sortrows(const int* __restrict__ cnt,
                                                    int* __restrict__ keys) {
    int row  = blockIdx.x * 4 + (threadIdx.x >> 6);
    int lane = threadIdx.x & 63;
    int len  = min(cnt[row], RCAP);
    int base = row * RCAP;
    int v = (lane < len) ? keys[base + lane] : 0x7FFFFFFF;

    #pragma unroll
    for (int k = 2; k <= 64; k <<= 1) {
        #pragma unroll
        for (int j = k >> 1; j >= 1; j >>= 1) {
            int p = __shfl_xor(v, j);
            bool asc = (lane & k) == 0;    // k=64: always ascending (lane<64)
            bool low = (lane & j) == 0;
            v = (low == asc) ? min(v, p) : max(v, p);
        }
    }
    int nxt = __shfl_down(v, 1);
    bool dead = (lane + 1 < len) && ((v >> 18) == (nxt >> 18));
    if (lane < len) keys[base + lane] = v | (dead ? 0x80000000 : 0);
}

// ---- flash attention: R10 structure (512 threads, BR=128, BC=64, 2 barriers/tile,
// per-wave bias walker) but with FIXED softmax shift m=66 (scores provably < 64):
// no online max, no alpha, no O-rescale, no msplit. exp(S-66) >= e^-130 is safe in
// fp32/bf16 (same exponent range); row max >= S_ii ~ 21 keeps l well-normalized.
__global__ __launch_bounds__(512) void cpa_flash(
    const short* __restrict__ Xbf, const short* __restrict__ Ybt,
    const float* __restrict__ es, const int* __restrict__ keys,
    const int* __restrict__ cnt,
    float* __restrict__ lsplit, short* __restrict__ Opart)
{
    __shared__ short Xj[BC][136];     // X tile (j rows), stride 136 (16B-aligned rows)
    __shared__ short Yt[DX][72];      // V tile K-transposed: Yt[feature][j-local]
    __shared__ short Pl[BR][72];      // P tile bf16; wave w touches rows 16w..16w+15 only

    const int tid   = threadIdx.x;
    const int lane  = tid & 63;
    const int w     = tid >> 6;       // wave 0..7 -> rows 16w..16w+15
    const int q     = lane >> 4;      // quad
    const int colid = lane & 15;

    const int ib = blockIdx.x;        // 0..63
    const int split = blockIdx.y;     // 0..SPLITS-1
    const int i0 = ib * BR;
    const int jstart = split * (N_NODES / SPLITS);

    // A-fragments straight from global (16B contiguous along features, one-time)
    short8 afrag[4];
    #pragma unroll
    for (int kf = 0; kf < 4; ++kf)
        afrag[kf] = *(const short8*)(Xbf + (size_t)(i0 + w * 16 + colid) * DX + kf * 32 + q * 8);

    // per-wave walker state: lane<16 owns row i0 + w*16 + lane
    int cur = 0, rend = 0;
    if (lane < 16) {
        int i = i0 + w * 16 + lane;
        cur = i * RCAP;
        rend = cur + min(cnt[i], RCAP);
        while (cur < rend) {
            int k = keys[cur];
            int dst = (k >> 18) & 0x1FFF;
            if (dst >= jstart) break;
            ++cur;
        }
    }

    float l_r[4] = {0.f, 0.f, 0.f, 0.f};
    f32x4 O[8];
    #pragma unroll
    for (int t = 0; t < 8; ++t) O[t] = (f32x4){0.f, 0.f, 0.f, 0.f};

    for (int tt = 0; tt < TILES; ++tt) {
        const int j0 = jstart + tt * BC;
        // phase A: stage X_j and Y_t tiles (cooperative, vectorized, 512 threads)
        for (int itr = 0; itr < 2; ++itr) {
            int idx = tid + itr * 512;            // 0..1023
            int r = idx >> 4;                     // 0..63
            int c8 = (idx & 15) << 3;
            *(int4*)(&Xj[r][c8]) = *(const int4*)(Xbf + (size_t)(j0 + r) * DX + c8);
        }
        for (int itr = 0; itr < 2; ++itr) {
            int idx = tid + itr * 512;            // 0..1023
            int n = idx >> 3;                     // 0..127
            int k8 = (idx & 7) << 3;
            *(int4*)(&Yt[n][k8]) = *(const int4*)(Ybt + (size_t)n * N_NODES + j0 + k8);
        }
        __syncthreads();  // B1

        // phase B: S = Xi·Xj^T (wave w: rows 16w..16w+15, cols 0..63)
        f32x4 S[4];
        #pragma unroll
        for (int st = 0; st < 4; ++st) {
            f32x4 acc = (f32x4){0.f, 0.f, 0.f, 0.f};
            #pragma unroll
            for (int kf = 0; kf < 4; ++kf) {
                short8 bfrag = *(const short8*)&Xj[st * 16 + colid][kf * 32 + q * 8];
                acc = __builtin_amdgcn_mfma_f32_16x16x32_bf16(afrag[kf], bfrag, acc, 0, 0, 0);
            }
            S[st] = acc;
        }
        // softmax numerators with FIXED shift (no max, no rescale)
        float rsum[4] = {0.f, 0.f, 0.f, 0.f};
        short pb[4][4];
        #pragma unroll
        for (int st = 0; st < 4; ++st) {
            #pragma unroll
            for (int r = 0; r < 4; ++r) {
                float p = __expf(S[st][r] - MSHIFT);
                rsum[r] += p;
                pb[st][r] = f2bf(p);
            }
        }
        #pragma unroll
        for (int r = 0; r < 4; ++r) {
            float s_ = rsum[r];
            s_ += __shfl_xor(s_, 1);
            s_ += __shfl_xor(s_, 2);
            s_ += __shfl_xor(s_, 4);
            s_ += __shfl_xor(s_, 8);
            l_r[r] += s_;
        }
        // phase C: P -> LDS (bf16) — own-wave rows only
        #pragma unroll
        for (int st = 0; st < 4; ++st)
            #pragma unroll
            for (int r = 0; r < 4; ++r)
                Pl[w * 16 + q * 4 + r][st * 16 + colid] = pb[st][r];

        // phase C2 (per-wave): lanes 0..15 bias-walk their own row; same-wave DS
        // ordering makes write->RMW->read safe without barriers.
        float dlocal = 0.f;
        if (lane < 16) {
            const int jend = j0 + BC;
            int c = cur;
            while (c < rend) {
                int k = keys[c];
                int dst = (k >> 18) & 0x1FFF;
                if (dst >= jend) break;
                ++c;
                if (k >= 0) {  // live (last duplicate wins)
                    int ec = dst - j0;
                    float old = bf2f(Pl[w * 16 + lane][ec]);
                    float nw = old * __expf(es[k & 0x3FFFF]);
                    Pl[w * 16 + lane][ec] = f2bf(nw);
                    dlocal += nw - old;
                }
            }
            cur = c;
        }
        // phase D: l += Δl (shuffle from owner lane); O += P·Y
        #pragma unroll
        for (int r = 0; r < 4; ++r)
            l_r[r] += __shfl(dlocal, q * 4 + r);

        short8 pf0 = *(const short8*)&Pl[w * 16 + colid][q * 8];
        short8 pf1 = *(const short8*)&Pl[w * 16 + colid][32 + q * 8];
        #pragma unroll
        for (int t = 0; t < 8; ++t) {
            short8 b0 = *(const short8*)&Yt[t * 16 + colid][q * 8];
            short8 b1 = *(const short8*)&Yt[t * 16 + colid][32 + q * 8];
            O[t] = __builtin_amdgcn_mfma_f32_16x16x32_bf16(pf0, b0, O[t], 0, 0, 0);
            O[t] = __builtin_amdgcn_mfma_f32_16x16x32_bf16(pf1, b1, O[t], 0, 0, 0);
        }
        __syncthreads();  // B4 (WAR: protect Xj/Yt for next iteration)
    }

    // epilogue: store partial l, O (O as bf16); fixed shift => merge is a plain sum
    const int ibase = i0 + w * 16 + q * 4;
    #pragma unroll
    for (int r = 0; r < 4; ++r) {
        if (colid == r)
            lsplit[(size_t)split * N_NODES + ibase + r] = l_r[r];
    }
    #pragma unroll
    for (int t = 0; t < 8; ++t) {
        #pragma unroll
        for (int r = 0; r < 4; ++r) {
            size_t off = ((size_t)split * N_NODES + ibase + r) * DX + t * 16 + colid;
            Opart[off] = f2bf(O[t][r]);
        }
    }
}

// ---- merge splits (plain sums) + normalize + write [new_mag | new_phase]
__global__ void cpa_merge(const float* __restrict__ lsplit, const short* __restrict__ Opart,
                          float* __restrict__ out) {
    int gid = blockIdx.x * 256 + threadIdx.x;   // N*128 threads
    int i = gid >> 7;
    int c = gid & 127;
    float den = 0.f, num = 0.f;
    #pragma unroll
    for (int s = 0; s < SPLITS; ++s) {
        den += lsplit[(size_t)s * N_NODES + i];
        num += bf2f(Opart[((size_t)s * N_NODES + i) * DX + c]);
    }
    float val = num / den;
    if (c < 64) out[(size_t)i * 64 + c] = val;
    else        out[(size_t)N_NODES * 64 + (size_t)i * 64 + (c - 64)] = val;
}

extern "C" void kernel_launch(void* const* d_in, const int* in_sizes, int n_in,
                              void* d_out, int out_size, void* d_ws, size_t ws_size,
                              hipStream_t stream)
{
    const float* mag   = (const float*)d_in[0];
    const float* phase = (const float*)d_in[1];
    const int*   ei    = (const int*)d_in[2];     // edge_index [2][E] (int32 per harness)
    const float* ea    = (const float*)d_in[3];
    const float* W     = (const float*)d_in[4];
    const float* b     = (const float*)d_in[5];
    float* out = (float*)d_out;

    char* ws = (char*)d_ws;
    short* Xbf    = (short*)(ws + 0);               // 2 MB
    short* Ybt    = (short*)(ws + 2097152);         // 2 MB
    float* es     = (float*)(ws + 4194304);         // 1 MB
    int*   keys   = (int*)  (ws + 5242880);         // 2 MB (8192 rows x 64 bins)
    int*   cnt    = (int*)  (ws + 7340032);         // 32 KB
    float* wsb    = (float*)(ws + 7372800);         // 256 B
    float* lsplit = (float*)(ws + 7373056);         // 256 KB (8 splits)
    short* Opart  = (short*)(ws + 7635200);         // 16 MB (bf16, 8 splits)

    hipMemsetAsync(cnt, 0, N_NODES * sizeof(int), stream);
    cpa_prep_w<<<1, 64, 0, stream>>>(W, b, wsb);
    cpa_prep_all<<<2048 + 256 + NEDGE / 256, 256, 0, stream>>>(mag, phase, ei, ea, wsb,
                                                               Xbf, Ybt, es, cnt, keys);
    cpa_sortrows<<<N_NODES / 4, 256, 0, stream>>>(cnt, keys);
    cpa_flash<<<dim3(N_NODES / BR, SPLITS), 512, 0, stream>>>(Xbf, Ybt, es, keys, cnt,
                                                              lsplit, Opart);
    cpa_merge<<<N_NODES * DX / 256, 256, 0, stream>>>(lsplit, Opart, out);
}

// Round 12
// 176.739 us; speedup vs baseline: 3.4268x; 1.0101x over previous
//
#include <hip/hip_runtime.h>
#include <hip/hip_bf16.h>
#include <cstdint>

#define N_NODES 8192
#define DDIM    64
#define DX      128
#define NEDGE   262144
#define BR      128                       // query rows per block (8 waves x 16)
#define BC      64                        // key/value columns per tile
#define SPLITS  8
#define TILES   (N_NODES / BC / SPLITS)   // 16 (compile-time)
#define RCAP    64                        // per-row edge bin capacity (Poisson(32), 5.7 sigma)
#define MSHIFT  66.0f                     // fixed softmax shift: scores < 64 always
#define PSTR    76                        // Pl row stride in shorts (38 dwords: kills 4-way store conflicts)

typedef float f32x4 __attribute__((ext_vector_type(4)));
typedef short short8 __attribute__((ext_vector_type(8)));

__device__ __forceinline__ short f2bf(float f) {
    union { float f; uint32_t u; } v; v.f = f;
    uint32_t u = v.u;
    uint32_t r = (u + 0x7FFFu + ((u >> 16) & 1u)) >> 16;
    return (short)r;
}
__device__ __forceinline__ float bf2f(short s) {
    union { uint32_t u; float f; } v;
    v.u = ((uint32_t)(uint16_t)s) << 16;
    return v.f;
}

// ---- fused prep: [0,2048) X-build, [2048,2304) Y-transpose, [2304,3328) edges
// Edge blocks self-compute the rank-1 Linear collapse (wsum, bsum) from W/b
// (1.3 KB, L2-hit) -- no separate prep_w dispatch. Direct per-row binning.
__global__ void cpa_prep_all(const float* __restrict__ mag, const float* __restrict__ phase,
                             const int* __restrict__ ei, const float* __restrict__ ea,
                             const float* __restrict__ W, const float* __restrict__ b,
                             short* __restrict__ Xbf, short* __restrict__ Ybt,
                             float* __restrict__ es, int* __restrict__ cnt,
                             int* __restrict__ keys) {
    __shared__ short tile[64][65];
    __shared__ float wsb[5];
    const int blk = blockIdx.x;
    const int tid = threadIdx.x;
    if (blk < 2048) {
        // X = [mag*cos(phase) | mag*sin(phase)] bf16 [N][128]
        int idx = blk * 256 + tid;                 // N*64 threads
        int i = idx >> 6, d = idx & 63;
        float m = mag[idx], p = phase[idx];
        Xbf[i * DX + d]      = f2bf(m * __cosf(p));
        Xbf[i * DX + 64 + d] = f2bf(m * __sinf(p));
    } else if (blk < 2304) {
        // Ybt[c][i] = bf16(Y[i][c]), Y = [mag | phase]
        int bb = blk - 2048;
        int bi = bb >> 1;
        int bc = bb & 1;
        int i0 = bi * 64;
        const float* src = bc ? phase : mag;
        for (int itr = 0; itr < 16; ++itr) {
            int idx = tid + itr * 256;             // 0..4095
            int ii = idx >> 6, cc = idx & 63;
            tile[ii][cc] = f2bf(src[(size_t)(i0 + ii) * 64 + cc]);
        }
        __syncthreads();
        for (int itr = 0; itr < 16; ++itr) {
            int idx = tid + itr * 256;
            int cc = idx >> 6, ii = idx & 63;
            Ybt[(size_t)(bc * 64 + cc) * N_NODES + i0 + ii] = tile[ii][cc];
        }
    } else {
        // wave 0: reduce W (rank-1 collapse) into LDS
        if (tid < 64) {
            float w0 = W[tid * 4 + 0], w1 = W[tid * 4 + 1];
            float w2 = W[tid * 4 + 2], w3 = W[tid * 4 + 3];
            float bb = b[tid];
            #pragma unroll
            for (int o = 32; o > 0; o >>= 1) {
                w0 += __shfl_down(w0, o);
                w1 += __shfl_down(w1, o);
                w2 += __shfl_down(w2, o);
                w3 += __shfl_down(w3, o);
                bb += __shfl_down(bb, o);
            }
            if (tid == 0) { wsb[0] = w0; wsb[1] = w1; wsb[2] = w2; wsb[3] = w3; wsb[4] = bb; }
        }
        __syncthreads();
        // edge scores + direct CSR binning, key = (dst<<18)|e
        int e = (blk - 2304) * 256 + tid;
        float4 a = *(const float4*)(ea + (size_t)e * 4);
        es[e] = a.x * wsb[0] + a.y * wsb[1] + a.z * wsb[2] + a.w * wsb[3] + wsb[4];
        int src = ei[e];
        int dst = ei[NEDGE + e];
        int pos = atomicAdd(&cnt[src], 1);
        if (pos < RCAP) keys[src * RCAP + pos] = (dst << 18) | e;
    }
}

// ---- per-row sort by (dst,e): one wave per row, 1 key/lane, 64-wide bitonic;
// mark all-but-last duplicate dst dead (numpy last-wins).
__global__ __launch_bounds__(256) void cpa_sortrows(const int* __restrict__ cnt,
                                                    int* __restrict__ keys) {
    int row  = blockIdx.x * 4 + (threadIdx.x >> 6);
    int lane = threadIdx.x & 63;
    int len  = min(cnt[row], RCAP);
    int base = row * RCAP;
    int v = (lane < len) ? keys[base + lane] : 0x7FFFFFFF;

    #pragma unroll
    for (int k = 2; k <= 64; k <<= 1) {
        #pragma unroll
        for (int j = k >> 1; j >= 1; j >>= 1) {
            int p = __shfl_xor(v, j);
            bool asc = (lane & k) == 0;    // k=64: always ascending (lane<64)
            bool low = (lane & j) == 0;
            v = (low == asc) ? min(v, p) : max(v, p);
        }
    }
    int nxt = __shfl_down(v, 1);
    bool dead = (lane + 1 < len) && ((v >> 18) == (nxt >> 18));
    if (lane < len) keys[base + lane] = v | (dead ? 0x80000000 : 0);
}

// ---- flash attention: R11 structure (512 threads, BR=128, BC=64, fixed shift,
// 2 barriers/tile, per-wave bias walker). Pl stride 76 shorts: P-store banks are
// 24q+6r+8st+(colid>>1) mod 32 -> full coverage, ~2 lanes/bank (free) instead of
// the 4-way conflict at stride 72.
__global__ __launch_bounds__(512) void cpa_flash(
    const short* __restrict__ Xbf, const short* __restrict__ Ybt,
    const float* __restrict__ es, const int* __restrict__ keys,
    const int* __restrict__ cnt,
    float* __restrict__ lsplit, short* __restrict__ Opart)
{
    __shared__ short Xj[BC][136];     // X tile (j rows), stride 136 (16B-aligned rows)
    __shared__ short Yt[DX][72];      // V tile K-transposed: Yt[feature][j-local]
    __shared__ short Pl[BR][PSTR];    // P tile bf16; wave w touches rows 16w..16w+15 only

    const int tid   = threadIdx.x;
    const int lane  = tid & 63;
    const int w     = tid >> 6;       // wave 0..7 -> rows 16w..16w+15
    const int q     = lane >> 4;      // quad
    const int colid = lane & 15;

    const int ib = blockIdx.x;        // 0..63
    const int split = blockIdx.y;     // 0..SPLITS-1
    const int i0 = ib * BR;
    const int jstart = split * (N_NODES / SPLITS);

    // A-fragments straight from global (16B contiguous along features, one-time)
    short8 afrag[4];
    #pragma unroll
    for (int kf = 0; kf < 4; ++kf)
        afrag[kf] = *(const short8*)(Xbf + (size_t)(i0 + w * 16 + colid) * DX + kf * 32 + q * 8);

    // per-wave walker state: lane<16 owns row i0 + w*16 + lane
    int cur = 0, rend = 0;
    if (lane < 16) {
        int i = i0 + w * 16 + lane;
        cur = i * RCAP;
        rend = cur + min(cnt[i], RCAP);
        while (cur < rend) {
            int k = keys[cur];
            int dst = (k >> 18) & 0x1FFF;
            if (dst >= jstart) break;
            ++cur;
        }
    }

    float l_r[4] = {0.f, 0.f, 0.f, 0.f};
    f32x4 O[8];
    #pragma unroll
    for (int t = 0; t < 8; ++t) O[t] = (f32x4){0.f, 0.f, 0.f, 0.f};

    for (int tt = 0; tt < TILES; ++tt) {
        const int j0 = jstart + tt * BC;
        // phase A: stage X_j and Y_t tiles (cooperative, vectorized, 512 threads)
        for (int itr = 0; itr < 2; ++itr) {
            int idx = tid + itr * 512;            // 0..1023
            int r = idx >> 4;                     // 0..63
            int c8 = (idx & 15) << 3;
            *(int4*)(&Xj[r][c8]) = *(const int4*)(Xbf + (size_t)(j0 + r) * DX + c8);
        }
        for (int itr = 0; itr < 2; ++itr) {
            int idx = tid + itr * 512;            // 0..1023
            int n = idx >> 3;                     // 0..127
            int k8 = (idx & 7) << 3;
            *(int4*)(&Yt[n][k8]) = *(const int4*)(Ybt + (size_t)n * N_NODES + j0 + k8);
        }
        __syncthreads();  // B1

        // phase B: S = Xi·Xj^T (wave w: rows 16w..16w+15, cols 0..63)
        f32x4 S[4];
        #pragma unroll
        for (int st = 0; st < 4; ++st) {
            f32x4 acc = (f32x4){0.f, 0.f, 0.f, 0.f};
            #pragma unroll
            for (int kf = 0; kf < 4; ++kf) {
                short8 bfrag = *(const short8*)&Xj[st * 16 + colid][kf * 32 + q * 8];
                acc = __builtin_amdgcn_mfma_f32_16x16x32_bf16(afrag[kf], bfrag, acc, 0, 0, 0);
            }
            S[st] = acc;
        }
        // softmax numerators with FIXED shift (no max, no rescale)
        float rsum[4] = {0.f, 0.f, 0.f, 0.f};
        short pb[4][4];
        #pragma unroll
        for (int st = 0; st < 4; ++st) {
            #pragma unroll
            for (int r = 0; r < 4; ++r) {
                float p = __expf(S[st][r] - MSHIFT);
                rsum[r] += p;
                pb[st][r] = f2bf(p);
            }
        }
        #pragma unroll
        for (int r = 0; r < 4; ++r) {
            float s_ = rsum[r];
            s_ += __shfl_xor(s_, 1);
            s_ += __shfl_xor(s_, 2);
            s_ += __shfl_xor(s_, 4);
            s_ += __shfl_xor(s_, 8);
            l_r[r] += s_;
        }
        // phase C: P -> LDS (bf16) — own-wave rows only
        #pragma unroll
        for (int st = 0; st < 4; ++st)
            #pragma unroll
            for (int r = 0; r < 4; ++r)
                Pl[w * 16 + q * 4 + r][st * 16 + colid] = pb[st][r];

        // phase C2 (per-wave): lanes 0..15 bias-walk their own row; same-wave DS
        // ordering makes write->RMW->read safe without barriers.
        float dlocal = 0.f;
        if (lane < 16) {
            const int jend = j0 + BC;
            int c = cur;
            while (c < rend) {
                int k = keys[c];
                int dst = (k >> 18) & 0x1FFF;
                if (dst >= jend) break;
                ++c;
                if (k >= 0) {  // live (last duplicate wins)
                    int ec = dst - j0;
                    float old = bf2f(Pl[w * 16 + lane][ec]);
                    float nw = old * __expf(es[k & 0x3FFFF]);
                    Pl[w * 16 + lane][ec] = f2bf(nw);
                    dlocal += nw - old;
                }
            }
            cur = c;
        }
        // phase D: l += Δl (shuffle from owner lane); O += P·Y
        #pragma unroll
        for (int r = 0; r < 4; ++r)
            l_r[r] += __shfl(dlocal, q * 4 + r);

        short8 pf0 = *(const short8*)&Pl[w * 16 + colid][q * 8];
        short8 pf1 = *(const short8*)&Pl[w * 16 + colid][32 + q * 8];
        #pragma unroll
        for (int t = 0; t < 8; ++t) {
            short8 b0 = *(const short8*)&Yt[t * 16 + colid][q * 8];
            short8 b1 = *(const short8*)&Yt[t * 16 + colid][32 + q * 8];
            O[t] = __builtin_amdgcn_mfma_f32_16x16x32_bf16(pf0, b0, O[t], 0, 0, 0);
            O[t] = __builtin_amdgcn_mfma_f32_16x16x32_bf16(pf1, b1, O[t], 0, 0, 0);
        }
        __syncthreads();  // B4 (WAR: protect Xj/Yt for next iteration)
    }

    // epilogue: store partial l, O (O as bf16); fixed shift => merge is a plain sum
    const int ibase = i0 + w * 16 + q * 4;
    #pragma unroll
    for (int r = 0; r < 4; ++r) {
        if (colid == r)
            lsplit[(size_t)split * N_NODES + ibase + r] = l_r[r];
    }
    #pragma unroll
    for (int t = 0; t < 8; ++t) {
        #pragma unroll
        for (int r = 0; r < 4; ++r) {
            size_t off = ((size_t)split * N_NODES + ibase + r) * DX + t * 16 + colid;
            Opart[off] = f2bf(O[t][r]);
        }
    }
}

// ---- merge splits (plain sums) + normalize + write [new_mag | new_phase]
__global__ void cpa_merge(const float* __restrict__ lsplit, const short* __restrict__ Opart,
                          float* __restrict__ out) {
    int gid = blockIdx.x * 256 + threadIdx.x;   // N*128 threads
    int i = gid >> 7;
    int c = gid & 127;
    float den = 0.f, num = 0.f;
    #pragma unroll
    for (int s = 0; s < SPLITS; ++s) {
        den += lsplit[(size_t)s * N_NODES + i];
        num += bf2f(Opart[((size_t)s * N_NODES + i) * DX + c]);
    }
    float val = num / den;
    if (c < 64) out[(size_t)i * 64 + c] = val;
    else        out[(size_t)N_NODES * 64 + (size_t)i * 64 + (c - 64)] = val;
}

extern "C" void kernel_launch(void* const* d_in, const int* in_sizes, int n_in,
                              void* d_out, int out_size, void* d_ws, size_t ws_size,
                              hipStream_t stream)
{
    const float* mag   = (const float*)d_in[0];
    const float* phase = (const float*)d_in[1];
    const int*   ei    = (const int*)d_in[2];     // edge_index [2][E] (int32 per harness)
    const float* ea    = (const float*)d_in[3];
    const float* W     = (const float*)d_in[4];
    const float* b     = (const float*)d_in[5];
    float* out = (float*)d_out;

    char* ws = (char*)d_ws;
    short* Xbf    = (short*)(ws + 0);               // 2 MB
    short* Ybt    = (short*)(ws + 2097152);         // 2 MB
    float* es     = (float*)(ws + 4194304);         // 1 MB
    int*   keys   = (int*)  (ws + 5242880);         // 2 MB (8192 rows x 64 bins)
    int*   cnt    = (int*)  (ws + 7340032);         // 32 KB
    float* lsplit = (float*)(ws + 7373056);         // 256 KB (8 splits)
    short* Opart  = (short*)(ws + 7635200);         // 16 MB (bf16, 8 splits)

    hipMemsetAsync(cnt, 0, N_NODES * sizeof(int), stream);
    cpa_prep_all<<<2048 + 256 + NEDGE / 256, 256, 0, stream>>>(mag, phase, ei, ea, W, b,
                                                               Xbf, Ybt, es, cnt, keys);
    cpa_sortrows<<<N_NODES / 4, 256, 0, stream>>>(cnt, keys);
    cpa_flash<<<dim3(N_NODES / BR, SPLITS), 512, 0, stream>>>(Xbf, Ybt, es, keys, cnt,
                                                              lsplit, Opart);
    cpa_merge<<<N_NODES * DX / 256, 256, 0, stream>>>(lsplit, Opart, out);
}

// Round 13
// 167.834 us; speedup vs baseline: 3.6086x; 1.0531x over previous
//
#include <hip/hip_runtime.h>
#include <hip/hip_bf16.h>
#include <cstdint>

#define N_NODES 8192
#define DDIM    64
#define DX      128
#define NEDGE   262144
#define BR      128                       // query rows per block (8 waves, 32x32 MFMA tiles)
#define BC      64                        // key/value columns per tile
#define SPLITS  8
#define TILES   (N_NODES / BC / SPLITS)   // 16 (compile-time)
#define RCAP    64                        // per-row edge bin capacity (Poisson(32), 5.7 sigma)
#define MSHIFT  66.0f                     // fixed softmax shift: scores < 64 always

typedef float f32x16 __attribute__((ext_vector_type(16)));
typedef short short8 __attribute__((ext_vector_type(8)));

__device__ __forceinline__ short f2bf(float f) {
    union { float f; uint32_t u; } v; v.f = f;
    uint32_t u = v.u;
    uint32_t r = (u + 0x7FFFu + ((u >> 16) & 1u)) >> 16;
    return (short)r;
}
__device__ __forceinline__ float bf2f(short s) {
    union { uint32_t u; float f; } v;
    v.u = ((uint32_t)(uint16_t)s) << 16;
    return v.f;
}

// ---- fused prep: [0,2048) X-build, [2048,2304) Y-transpose, [2304,3328) edges
__global__ void cpa_prep_all(const float* __restrict__ mag, const float* __restrict__ phase,
                             const int* __restrict__ ei, const float* __restrict__ ea,
                             const float* __restrict__ W, const float* __restrict__ b,
                             short* __restrict__ Xbf, short* __restrict__ Ybt,
                             float* __restrict__ es, int* __restrict__ cnt,
                             int* __restrict__ keys) {
    __shared__ short tile[64][65];
    __shared__ float wsb[5];
    const int blk = blockIdx.x;
    const int tid = threadIdx.x;
    if (blk < 2048) {
        int idx = blk * 256 + tid;                 // N*64 threads
        int i = idx >> 6, d = idx & 63;
        float m = mag[idx], p = phase[idx];
        Xbf[i * DX + d]      = f2bf(m * __cosf(p));
        Xbf[i * DX + 64 + d] = f2bf(m * __sinf(p));
    } else if (blk < 2304) {
        int bb = blk - 2048;
        int bi = bb >> 1;
        int bc = bb & 1;
        int i0 = bi * 64;
        const float* src = bc ? phase : mag;
        for (int itr = 0; itr < 16; ++itr) {
            int idx = tid + itr * 256;             // 0..4095
            int ii = idx >> 6, cc = idx & 63;
            tile[ii][cc] = f2bf(src[(size_t)(i0 + ii) * 64 + cc]);
        }
        __syncthreads();
        for (int itr = 0; itr < 16; ++itr) {
            int idx = tid + itr * 256;
            int cc = idx >> 6, ii = idx & 63;
            Ybt[(size_t)(bc * 64 + cc) * N_NODES + i0 + ii] = tile[ii][cc];
        }
    } else {
        if (tid < 64) {
            float w0 = W[tid * 4 + 0], w1 = W[tid * 4 + 1];
            float w2 = W[tid * 4 + 2], w3 = W[tid * 4 + 3];
            float bb = b[tid];
            #pragma unroll
            for (int o = 32; o > 0; o >>= 1) {
                w0 += __shfl_down(w0, o);
                w1 += __shfl_down(w1, o);
                w2 += __shfl_down(w2, o);
                w3 += __shfl_down(w3, o);
                bb += __shfl_down(bb, o);
            }
            if (tid == 0) { wsb[0] = w0; wsb[1] = w1; wsb[2] = w2; wsb[3] = w3; wsb[4] = bb; }
        }
        __syncthreads();
        int e = (blk - 2304) * 256 + tid;
        float4 a = *(const float4*)(ea + (size_t)e * 4);
        es[e] = a.x * wsb[0] + a.y * wsb[1] + a.z * wsb[2] + a.w * wsb[3] + wsb[4];
        int src = ei[e];
        int dst = ei[NEDGE + e];
        int pos = atomicAdd(&cnt[src], 1);
        if (pos < RCAP) keys[src * RCAP + pos] = (dst << 18) | e;
    }
}

// ---- per-row sort by (dst,e): one wave per row, 1 key/lane, 64-wide bitonic;
// mark all-but-last duplicate dst dead (numpy last-wins).
__global__ __launch_bounds__(256) void cpa_sortrows(const int* __restrict__ cnt,
                                                    int* __restrict__ keys) {
    int row  = blockIdx.x * 4 + (threadIdx.x >> 6);
    int lane = threadIdx.x & 63;
    int len  = min(cnt[row], RCAP);
    int base = row * RCAP;
    int v = (lane < len) ? keys[base + lane] : 0x7FFFFFFF;

    #pragma unroll
    for (int k = 2; k <= 64; k <<= 1) {
        #pragma unroll
        for (int j = k >> 1; j >= 1; j >>= 1) {
            int p = __shfl_xor(v, j);
            bool asc = (lane & k) == 0;
            bool low = (lane & j) == 0;
            v = (low == asc) ? min(v, p) : max(v, p);
        }
    }
    int nxt = __shfl_down(v, 1);
    bool dead = (lane + 1 < len) && ((v >> 18) == (nxt >> 18));
    if (lane < len) keys[base + lane] = v | (dead ? 0x80000000 : 0);
}

// ---- flash attention, 32x32x16 MFMA core. 512 threads / 8 waves; wave w:
// S-tile (rg=w>>1 rows, cg=w&1 cols) -> 8 B-frag LDS reads/tile (was 16);
// PV: out row-group rg x 2 col tiles sharing A-frags -> 12 reads (was 18).
// Block LDS reads 160 b128/tile vs 272 with the 16x16 core. Bias RMW stays
// same-wave (wave owns Pl rows rg*32.. cols cg*32..). l = P x ones-vector via
// 4 extra MFMA on even waves (free A-frag reuse) -- no shuffles, no delta-l.
// Layouts: C/D col=lane&31, row=(reg&3)+8(reg>>2)+4(lane>>5) [m74/m101];
// A m=lane&31, k=(lane>>5)*8+j; B n=lane&31, k=(lane>>5)*8+j.
__global__ __launch_bounds__(512, 4) void cpa_flash(
    const short* __restrict__ Xbf, const short* __restrict__ Ybt,
    const float* __restrict__ es, const int* __restrict__ keys,
    const int* __restrict__ cnt,
    float* __restrict__ lsplit, short* __restrict__ Opart)
{
    __shared__ short Xj[BC][136];     // X tile (j rows), stride 136
    __shared__ short Yt[DX][72];      // V tile K-transposed: Yt[feature][j-local]
    __shared__ short Pl[BR][72];      // P tile; stride 72: store banks split 16/16 by lane-half

    const int tid  = threadIdx.x;
    const int lane = tid & 63;
    const int w    = tid >> 6;        // wave 0..7
    const int l31  = lane & 31;
    const int lh   = lane >> 5;       // K-half within fragment
    const int rg   = w >> 1;          // row group (32 rows), S and PV
    const int cg   = w & 1;           // S col group / P region half
    const int ocg0 = (w & 1) * 2;     // PV col-tile pair {ocg0, ocg0+1}

    const int ib = blockIdx.x;        // 0..63
    const int split = blockIdx.y;     // 0..SPLITS-1
    const int i0 = ib * BR;
    const int jstart = split * (N_NODES / SPLITS);

    // Xi A-fragments: rows rg*32+l31, 8 K-chunks of 16 over 128 features (global, once)
    short8 afrag[8];
    #pragma unroll
    for (int kf = 0; kf < 8; ++kf)
        afrag[kf] = *(const short8*)(Xbf + (size_t)(i0 + rg * 32 + l31) * DX + kf * 16 + lh * 8);

    short8 ones;
    #pragma unroll
    for (int j = 0; j < 8; ++j) ones[j] = (short)0x3F80;   // bf16 1.0

    // walker cursor: lane<32 owns row i0 + rg*32 + lane
    int cur = 0, rend = 0;
    if (lane < 32) {
        int i = i0 + rg * 32 + l31;
        cur = i * RCAP;
        rend = cur + min(cnt[i], RCAP);
        while (cur < rend) {
            int k = keys[cur];
            if (((k >> 18) & 0x1FFF) >= jstart) break;
            ++cur;
        }
    }

    f32x16 O0, O1, lC;
    #pragma unroll
    for (int r = 0; r < 16; ++r) { O0[r] = 0.f; O1[r] = 0.f; lC[r] = 0.f; }

    for (int tt = 0; tt < TILES; ++tt) {
        const int j0 = jstart + tt * BC;
        // phase A: stage X_j and Y_t tiles
        for (int itr = 0; itr < 2; ++itr) {
            int idx = tid + itr * 512;
            int r = idx >> 4;
            int c8 = (idx & 15) << 3;
            *(int4*)(&Xj[r][c8]) = *(const int4*)(Xbf + (size_t)(j0 + r) * DX + c8);
        }
        for (int itr = 0; itr < 2; ++itr) {
            int idx = tid + itr * 512;
            int n = idx >> 3;
            int k8 = (idx & 7) << 3;
            *(int4*)(&Yt[n][k8]) = *(const int4*)(Ybt + (size_t)n * N_NODES + j0 + k8);
        }
        __syncthreads();  // B1: staging visible

        // phase B: S (32x32) = Xi(rg) · Xj(cg)^T, 8 K-steps
        f32x16 S;
        #pragma unroll
        for (int r = 0; r < 16; ++r) S[r] = 0.f;
        #pragma unroll
        for (int kf = 0; kf < 8; ++kf) {
            short8 bfrag = *(const short8*)&Xj[cg * 32 + l31][kf * 16 + lh * 8];
            S = __builtin_amdgcn_mfma_f32_32x32x16_bf16(afrag[kf], bfrag, S, 0, 0, 0);
        }
        // p = exp(S - 66) -> own Pl region (row rg*32+rowl, col cg*32+l31)
        #pragma unroll
        for (int r = 0; r < 16; ++r) {
            int rowl = 4 * lh + (r & 3) + 8 * (r >> 2);
            Pl[rg * 32 + rowl][cg * 32 + l31] = f2bf(__expf(S[r] - MSHIFT));
        }
        // bias RMW on own region (same-wave DS ordering; lanes 0..31)
        if (lane < 32) {
            const int jend = j0 + BC;
            const int wlo = j0 + cg * 32;
            int c = cur;
            while (c < rend) {
                int k = keys[c];
                int dst = (k >> 18) & 0x1FFF;
                if (dst >= jend) break;
                ++c;
                if (k >= 0) {
                    unsigned cl = (unsigned)(dst - wlo);
                    if (cl < 32u) {
                        short* p = &Pl[rg * 32 + l31][cg * 32 + (int)cl];
                        *p = f2bf(bf2f(*p) * __expf(es[k & 0x3FFFF]));
                    }
                }
            }
            cur = c;
        }
        __syncthreads();  // B2: biased P visible to all waves

        // phase D: O += P·Y (2 col tiles sharing A-frags); l += P·1 (even waves)
        #pragma unroll
        for (int ks = 0; ks < 4; ++ks) {
            short8 pa  = *(const short8*)&Pl[rg * 32 + l31][ks * 16 + lh * 8];
            short8 yb0 = *(const short8*)&Yt[ocg0 * 32 + l31][ks * 16 + lh * 8];
            short8 yb1 = *(const short8*)&Yt[(ocg0 + 1) * 32 + l31][ks * 16 + lh * 8];
            O0 = __builtin_amdgcn_mfma_f32_32x32x16_bf16(pa, yb0, O0, 0, 0, 0);
            O1 = __builtin_amdgcn_mfma_f32_32x32x16_bf16(pa, yb1, O1, 0, 0, 0);
            if (!(w & 1))
                lC = __builtin_amdgcn_mfma_f32_32x32x16_bf16(pa, ones, lC, 0, 0, 0);
        }
        __syncthreads();  // B4: WAR before next staging / P-store
    }

    // epilogue: O (bf16) and l (fixed shift => merge is a plain sum)
    #pragma unroll
    for (int r = 0; r < 16; ++r) {
        int row = rg * 32 + 4 * lh + (r & 3) + 8 * (r >> 2);
        size_t base = ((size_t)split * N_NODES + i0 + row) * DX;
        Opart[base + ocg0 * 32 + l31]       = f2bf(O0[r]);
        Opart[base + (ocg0 + 1) * 32 + l31] = f2bf(O1[r]);
    }
    if (!(w & 1) && l31 == 0) {
        #pragma unroll
        for (int r = 0; r < 16; ++r) {
            int row = rg * 32 + 4 * lh + (r & 3) + 8 * (r >> 2);
            lsplit[(size_t)split * N_NODES + i0 + row] = lC[r];
        }
    }
}

// ---- merge splits (plain sums) + normalize + write [new_mag | new_phase]
__global__ void cpa_merge(const float* __restrict__ lsplit, const short* __restrict__ Opart,
                          float* __restrict__ out) {
    int gid = blockIdx.x * 256 + threadIdx.x;   // N*128 threads
    int i = gid >> 7;
    int c = gid & 127;
    float den = 0.f, num = 0.f;
    #pragma unroll
    for (int s = 0; s < SPLITS; ++s) {
        den += lsplit[(size_t)s * N_NODES + i];
        num += bf2f(Opart[((size_t)s * N_NODES + i) * DX + c]);
    }
    float val = num / den;
    if (c < 64) out[(size_t)i * 64 + c] = val;
    else        out[(size_t)N_NODES * 64 + (size_t)i * 64 + (c - 64)] = val;
}

extern "C" void kernel_launch(void* const* d_in, const int* in_sizes, int n_in,
                              void* d_out, int out_size, void* d_ws, size_t ws_size,
                              hipStream_t stream)
{
    const float* mag   = (const float*)d_in[0];
    const float* phase = (const float*)d_in[1];
    const int*   ei    = (const int*)d_in[2];     // edge_index [2][E] (int32 per harness)
    const float* ea    = (const float*)d_in[3];
    const float* W     = (const float*)d_in[4];
    const float* b     = (const float*)d_in[5];
    float* out = (float*)d_out;

    char* ws = (char*)d_ws;
    short* Xbf    = (short*)(ws + 0);               // 2 MB
    short* Ybt    = (short*)(ws + 2097152);         // 2 MB
    float* es     = (float*)(ws + 4194304);         // 1 MB
    int*   keys   = (int*)  (ws + 5242880);         // 2 MB (8192 rows x 64 bins)
    int*   cnt    = (int*)  (ws + 7340032);         // 32 KB
    float* lsplit = (float*)(ws + 7373056);         // 256 KB (8 splits)
    short* Opart  = (short*)(ws + 7635200);         // 16 MB (bf16, 8 splits)

    hipMemsetAsync(cnt, 0, N_NODES * sizeof(int), stream);
    cpa_prep_all<<<2048 + 256 + NEDGE / 256, 256, 0, stream>>>(mag, phase, ei, ea, W, b,
                                                               Xbf, Ybt, es, cnt, keys);
    cpa_sortrows<<<N_NODES / 4, 256, 0, stream>>>(cnt, keys);
    cpa_flash<<<dim3(N_NODES / BR, SPLITS), 512, 0, stream>>>(Xbf, Ybt, es, keys, cnt,
                                                              lsplit, Opart);
    cpa_merge<<<N_NODES * DX / 256, 256, 0, stream>>>(lsplit, Opart, out);
}